// Round 5
// baseline (5433.717 us; speedup 1.0000x reference)
//
#include <hip/hip_runtime.h>
#include <math.h>

#define NN 60000
#define BB 8
#define GS 7500   // nodes per graph
#define FF 384
#define EE 600000
#define HH 6
#define CC 10
#define HT_BITS 20
#define HT_SIZE (1u << HT_BITS)
#define HT_MASK (HT_SIZE - 1u)
#define TPB 256
#define CAP 80000  // per-graph edge capacity (mean 75000, sigma ~256)
#define REMW ((GS + 31) / 32)
#define NBANDS 97  // score in [0.5,1.5]; band = (0x3FC00000 - bits(score)) >> 17
#define CPAD 16    // counter padding: 64B apart (R3 lesson: same-line atomics serialize)

static inline int ngrid(int n) { return (n + TPB - 1) / TPB; }

// ---------- helpers ----------
__device__ __forceinline__ unsigned int encf(float v) {
  unsigned int b = __float_as_uint(v);
  return (b & 0x80000000u) ? ~b : (b | 0x80000000u);
}
__device__ __forceinline__ float decf(unsigned int u) {
  unsigned int b = (u & 0x80000000u) ? (u & 0x7FFFFFFFu) : ~u;
  return __uint_as_float(b);
}
__device__ __forceinline__ int band_of(float sc) {
  unsigned int u = __float_as_uint(sc);
  int b = (int)((int)(0x3FC00000u - u) >> 17);
  return b < 0 ? 0 : (b > NBANDS - 1 ? NBANDS - 1 : b);
}

// ---------- stage 1 matmul: h1pre = x @ W1 (N x 384 @ 384 x 6) ----------
__global__ void k_mm1(const float* __restrict__ x, const float* __restrict__ W,
                      float* __restrict__ out) {
  __shared__ float Ws[FF * HH];
  for (int i = threadIdx.x; i < FF * HH; i += blockDim.x) Ws[i] = W[i];
  __syncthreads();
  int wave = threadIdx.x >> 6, lane = threadIdx.x & 63;
  int node = blockIdx.x * 4 + wave;
  if (node >= NN) return;
  const float* xr = x + (size_t)node * FF;
  float acc[HH] = {0.f, 0.f, 0.f, 0.f, 0.f, 0.f};
  for (int k = lane; k < FF; k += 64) {
    float xv = xr[k];
#pragma unroll
    for (int j = 0; j < HH; j++) acc[j] += xv * Ws[k * HH + j];
  }
#pragma unroll
  for (int j = 0; j < HH; j++) {
#pragma unroll
    for (int o = 32; o > 0; o >>= 1) acc[j] += __shfl_down(acc[j], o, 64);
  }
  if (lane == 0) {
#pragma unroll
    for (int j = 0; j < HH; j++) out[(size_t)node * HH + j] = acc[j];
  }
}

// ---------- stage 2 matmul ----------
__global__ void k_mm2(const float* __restrict__ x, const float* __restrict__ W,
                      float* __restrict__ out) {
  int v = blockIdx.x * blockDim.x + threadIdx.x;
  if (v >= NN) return;
  float xv[HH];
#pragma unroll
  for (int j = 0; j < HH; j++) xv[j] = x[(size_t)v * HH + j];
#pragma unroll
  for (int c = 0; c < CC; c++) {
    float a = 0.f;
#pragma unroll
    for (int j = 0; j < HH; j++) a += xv[j] * W[j * CC + c];
    out[(size_t)v * CC + c] = a;
  }
}

// ---------- fused per-stage zeroing ----------
__global__ void k_prep(float* __restrict__ deg, unsigned char* __restrict__ hasloop,
                       unsigned int* __restrict__ mEnc, float* __restrict__ ssum,
                       float* __restrict__ hout, int fd, int* __restrict__ cnt,
                       float* __restrict__ gsum, float* __restrict__ gcnt) {
  int v = blockIdx.x * blockDim.x + threadIdx.x;
  if (v >= NN) return;
  deg[v] = 0.f;
  hasloop[v] = 0;
  mEnc[v] = 0;
  ssum[v] = 0.f;
  for (int j = 0; j < fd; j++) hout[(size_t)v * fd + j] = 0.f;
  if (v < BB * NBANDS * CPAD) cnt[v] = 0;
  if (v < BB * CC) gsum[v] = 0.f;
  if (v < BB) gcnt[v] = 0.f;
}

// ---------- generic GCN conv pieces ----------
__global__ void k_deg(const int* __restrict__ src, const int* __restrict__ dst,
                      const unsigned char* __restrict__ ev, float* __restrict__ deg,
                      unsigned char* __restrict__ hasloop) {
  int e = blockIdx.x * blockDim.x + threadIdx.x;
  if (e >= EE) return;
  if (ev && !ev[e]) return;
  int d = dst[e];
  atomicAdd(&deg[d], 1.0f);
  if (src[e] == d) hasloop[d] = 1;
}

__global__ void k_dinv(const float* __restrict__ deg, const unsigned char* __restrict__ hasloop,
                       const unsigned char* __restrict__ nv, float* __restrict__ dinv,
                       unsigned char* __restrict__ addloop) {
  int v = blockIdx.x * blockDim.x + threadIdx.x;
  if (v >= NN) return;
  int nvv = nv ? (int)nv[v] : 1;
  unsigned char al = (nvv && !hasloop[v]) ? 1 : 0;
  float d = deg[v] + (float)al;
  dinv[v] = d > 0.f ? 1.0f / sqrtf(fmaxf(d, 1e-12f)) : 0.f;
  addloop[v] = al;
}

__global__ void k_gcn_agg(const int* __restrict__ src, const int* __restrict__ dst,
                          const unsigned char* __restrict__ ev, const float* __restrict__ dinv,
                          const float* __restrict__ h, float* __restrict__ out, int fd) {
  int e = blockIdx.x * blockDim.x + threadIdx.x;
  if (e >= EE) return;
  if (ev && !ev[e]) return;
  int s = src[e], d = dst[e];
  float c = dinv[s] * dinv[d];
  for (int j = 0; j < fd; j++)
    atomicAdd(&out[(size_t)d * fd + j], h[(size_t)s * fd + j] * c);
}

__global__ void k_gcn_fin(const float* __restrict__ h, const float* __restrict__ dinv,
                          const unsigned char* __restrict__ addloop, const float* __restrict__ b,
                          float* __restrict__ out, int fd, int relu) {
  int v = blockIdx.x * blockDim.x + threadIdx.x;
  if (v >= NN) return;
  float c = addloop[v] ? dinv[v] * dinv[v] : 0.f;
  for (int j = 0; j < fd; j++) {
    float o = out[(size_t)v * fd + j] + c * h[(size_t)v * fd + j] + b[j];
    if (relu) o = fmaxf(o, 0.f);
    out[(size_t)v * fd + j] = o;
  }
}

// ---------- edge pool: scores ----------
__global__ void k_raw(const float* __restrict__ x, const int* __restrict__ src,
                      const int* __restrict__ dst, const unsigned char* __restrict__ ev,
                      const float* __restrict__ Wp, const float* __restrict__ bp,
                      float* __restrict__ raw, unsigned int* __restrict__ mEnc, int fd) {
  int e = blockIdx.x * blockDim.x + threadIdx.x;
  if (e >= EE) return;
  if (ev && !ev[e]) return;
  int s = src[e], d = dst[e];
  float r = bp[0];
  for (int j = 0; j < fd; j++) r += x[(size_t)s * fd + j] * Wp[j];
  for (int j = 0; j < fd; j++) r += x[(size_t)d * fd + j] * Wp[fd + j];
  raw[e] = r;
  atomicMax(&mEnc[d], encf(r));
}

__global__ void k_exps(const float* __restrict__ raw, const int* __restrict__ dst,
                       const unsigned char* __restrict__ ev, const unsigned int* __restrict__ mEnc,
                       float* __restrict__ ex, float* __restrict__ ssum) {
  int e = blockIdx.x * blockDim.x + threadIdx.x;
  if (e >= EE) return;
  if (ev && !ev[e]) return;
  int d = dst[e];
  unsigned int me = mEnc[d];
  float m = me ? decf(me) : 0.f;
  float v = expf(raw[e] - m);
  ex[e] = v;
  atomicAdd(&ssum[d], v);
}

// score + per-(graph,band) counting (padded counters: disjoint 64B lines)
__global__ void k_score(const float* __restrict__ ex, const int* __restrict__ dst,
                        const unsigned char* __restrict__ ev, const float* __restrict__ ssum,
                        float* __restrict__ score, int* __restrict__ cnt) {
  int e = blockIdx.x * blockDim.x + threadIdx.x;
  if (e >= EE) return;
  if (ev && !ev[e]) return;
  int d = dst[e];
  float sd = ssum[d];
  float sc = ex[e] / (sd > 0.f ? sd : 1.0f) + 0.5f;
  score[e] = sc;
  int g = d / GS;
  atomicAdd(&cnt[(g * NBANDS + band_of(sc)) * CPAD], 1);
}

// ---------- exclusive scan of band counts -> offsets + scatter cursors ----------
__global__ void k_scan(const int* __restrict__ cnt, int* __restrict__ bandoff,
                       int* __restrict__ cursors) {
  int g = threadIdx.x;
  if (g >= BB) return;
  int off = 0;
  for (int b = 0; b < NBANDS; b++) {
    int c = cnt[(g * NBANDS + b) * CPAD];
    bandoff[g * NBANDS + b] = off;
    cursors[(g * NBANDS + b) * CPAD] = off;
    off += c;
  }
}

// ---------- scatter edges into per-(graph,band) regions; zero chosen ----------
__global__ void k_part(const int* __restrict__ src, const int* __restrict__ dst,
                       const float* __restrict__ score, const unsigned char* __restrict__ ev,
                       ulonglong2* __restrict__ recsB, int* __restrict__ cursors,
                       unsigned char* __restrict__ chosen) {
  int e = blockIdx.x * blockDim.x + threadIdx.x;
  if (e >= EE) return;
  chosen[e] = 0;
  if (ev && !ev[e]) return;
  int s = src[e], d = dst[e], g = s / GS;
  float sc = score[e];
  unsigned long long p = (((unsigned long long)__float_as_uint(sc)) << 32) |
                         (unsigned int)(~(unsigned int)e);
  int pos = atomicAdd(&cursors[(g * NBANDS + band_of(sc)) * CPAD], 1);
  recsB[(size_t)g * CAP + pos] =
      make_ulonglong2(p, (((unsigned long long)(unsigned int)s) << 32) | (unsigned int)d);
}

// ---------- matching: banded exact greedy ----------
// Bands descend in score (equal scores share a band). Per band: filter live ->
// if <=2048: single-wave LDS bitonic sort (full 64b prio) + 64-wide ballot-greedy
// (exact sequential order); else: in-band locally-dominant fixpoint until <=2048.
__global__ __launch_bounds__(1024) void k_match_g(
    const ulonglong2* __restrict__ recsB, ulonglong2* __restrict__ scrA,
    ulonglong2* __restrict__ scrB, const int* __restrict__ cnt,
    const int* __restrict__ bandoff, const unsigned char* __restrict__ nv,
    unsigned char* __restrict__ chosen) {
  __shared__ __align__(16) unsigned long long best[GS];  // 60KB; first 32KB aliased as sort buf
  __shared__ unsigned int remB[REMW];
  __shared__ int cntL, cnt2, dirtyF;
  ulonglong2* srt = (ulonglong2*)best;  // 2048 records
  const int g = blockIdx.x, base = g * GS;
  const int t = threadIdx.x, nth = blockDim.x, lane = t & 63;

  for (int w = t; w < REMW; w += nth) {
    unsigned int bits = 0;
    for (int b = 0; b < 32; b++) {
      int v = w * 32 + b;
      if (v < GS) bits |= (nv ? (nv[base + v] ? 1u : 0u) : 1u) << b;
    }
    remB[w] = bits;
  }
  for (int i = t; i < GS; i += nth) best[i] = 0ULL;
  if (t == 0) dirtyF = 0;
  __syncthreads();

  const ulonglong2* gRec = recsB + (size_t)g * CAP;
  ulonglong2* gA = scrA + (size_t)g * CAP;
  ulonglong2* gB = scrB + (size_t)g * CAP;

  for (int b = 0; b < NBANDS; b++) {
    int nb = cnt[(g * NBANDS + b) * CPAD];
    if (nb == 0) continue;
    const ulonglong2* bp = gRec + bandoff[g * NBANDS + b];
    if (t == 0) cntL = 0;
    __syncthreads();
    // filter live -> gA (4x batched loads for MLP)
    for (int i0 = 0; i0 < nb; i0 += nth * 4) {
      ulonglong2 r[4];
      int have[4];
#pragma unroll
      for (int k = 0; k < 4; k++) {
        int i = i0 + t + k * nth;
        have[k] = i < nb;
        if (have[k]) r[k] = bp[i];
      }
#pragma unroll
      for (int k = 0; k < 4; k++) {
        int live = 0;
        if (have[k]) {
          int ls = (int)(r[k].y >> 32) - base, ld = (int)(r[k].y & 0xFFFFFFFFu) - base;
          live = ((remB[ls >> 5] >> (ls & 31)) & 1u) && ((remB[ld >> 5] >> (ld & 31)) & 1u);
        }
        unsigned long long m = __ballot(live);
        int tot = __popcll(m);
        int pre = __popcll(m & ((1ULL << lane) - 1ULL));
        int b0 = 0;
        if (lane == 0 && tot) b0 = atomicAdd(&cntL, tot);
        b0 = __shfl(b0, 0, 64);
        if (live) gA[b0 + pre] = r[k];
      }
    }
    __syncthreads();
    int nL = cntL;
    ulonglong2 *ping = gA, *pong = gB;
    while (nL > 2048) {
      if (dirtyF) {
        for (int i = t; i < GS; i += nth) best[i] = 0ULL;
      }
      if (t == 0) { dirtyF = 0; cnt2 = 0; }
      __syncthreads();
      // P1: post priorities
      for (int i = t; i < nL; i += nth) {
        ulonglong2 r = ping[i];
        int ls = (int)(r.y >> 32) - base, ld = (int)(r.y & 0xFFFFFFFFu) - base;
        if (((remB[ls >> 5] >> (ls & 31)) & 1u) && ((remB[ld >> 5] >> (ld & 31)) & 1u)) {
          atomicMax(&best[ls], r.x);
          if (ld != ls) atomicMax(&best[ld], r.x);
        }
      }
      __syncthreads();
      // P2: winners commit; survivors -> pong
      for (int i = t; i < nL; i += nth) {
        ulonglong2 r = ping[i];
        int ls = (int)(r.y >> 32) - base, ld = (int)(r.y & 0xFFFFFFFFu) - base;
        int keep = 0;
        if (((remB[ls >> 5] >> (ls & 31)) & 1u) && ((remB[ld >> 5] >> (ld & 31)) & 1u)) {
          if (best[ls] == r.x && best[ld] == r.x) {
            int e = (int)(~(unsigned int)(r.x & 0xFFFFFFFFu));
            chosen[e] = 1;
            atomicAnd(&remB[ls >> 5], ~(1u << (ls & 31)));
            atomicAnd(&remB[ld >> 5], ~(1u << (ld & 31)));
          } else {
            keep = 1;
          }
        }
        unsigned long long m = __ballot(keep);
        int tot = __popcll(m);
        int pre = __popcll(m & ((1ULL << lane) - 1ULL));
        int b0 = 0;
        if (lane == 0 && tot) b0 = atomicAdd(&cnt2, tot);
        b0 = __shfl(b0, 0, 64);
        if (keep) pong[b0 + pre] = r;
      }
      __syncthreads();
      nL = cnt2;
      // P3: clear best at survivors' endpoints
      for (int i = t; i < nL; i += nth) {
        ulonglong2 r = pong[i];
        best[(int)(r.y >> 32) - base] = 0ULL;
        best[(int)(r.y & 0xFFFFFFFFu) - base] = 0ULL;
      }
      __syncthreads();
      ulonglong2* tmp = ping; ping = pong; pong = tmp;
    }
    if (nL > 0) {
      int np = 1;
      while (np < nL) np <<= 1;
      for (int i = t; i < np; i += nth)
        srt[i] = (i < nL) ? ping[i] : make_ulonglong2(0ULL, 0ULL);
      if (t == 0) dirtyF = 1;
      __syncthreads();
      if (t < 64) {
        // single-wave bitonic sort desc by full 64b prio (DS pipe is in-order per wave)
        for (int k = 2; k <= np; k <<= 1) {
          for (int j = k >> 1; j >= 1; j >>= 1) {
            for (int i = lane; i < np; i += 64) {
              int ixj = i ^ j;
              if (ixj > i) {
                ulonglong2 a = srt[i], c = srt[ixj];
                bool desc = ((i & k) == 0);
                if (desc ? (a.x < c.x) : (a.x > c.x)) { srt[i] = c; srt[ixj] = a; }
              }
            }
          }
        }
        // 64-wide chunks in sorted order: exact sequential greedy
        for (int c0 = 0; c0 < nL; c0 += 64) {
          int idx = c0 + lane;
          ulonglong2 r = (idx < np) ? srt[idx] : make_ulonglong2(0ULL, 0ULL);
          unsigned long long p = r.x;
          int ls = 0, ld = 0, alive = 0;
          if (p) {
            ls = (int)(r.y >> 32) - base;
            ld = (int)(r.y & 0xFFFFFFFFu) - base;
            alive = ((remB[ls >> 5] >> (ls & 31)) & 1u) && ((remB[ld >> 5] >> (ld & 31)) & 1u);
          }
          unsigned long long am = __ballot(alive), done = 0ULL;
          while (true) {
            unsigned long long rest = am & ~done;
            if (!rest) break;
            int i = __ffsll((long long)rest) - 1;
            int si = __shfl(ls, i, 64), di = __shfl(ld, i, 64);
            if (lane > i && alive && (ls == si || ls == di || ld == si || ld == di)) alive = 0;
            done |= 1ULL << i;
            am = __ballot(alive);
          }
          if (alive) {  // matched
            int e = (int)(~(unsigned int)(p & 0xFFFFFFFFu));
            chosen[e] = 1;
            atomicAnd(&remB[ls >> 5], ~(1u << (ls & 31)));
            atomicAnd(&remB[ld >> 5], ~(1u << (ld & 31)));
          }
        }
      }
      __syncthreads();
    }
  }
}

// ---------- edge pool: post-matching ----------
__global__ void k_pool_node(const unsigned char* __restrict__ nvin, unsigned char* __restrict__ nvout,
                            float* __restrict__ scale, int* __restrict__ merged,
                            float* __restrict__ added, int fd) {
  int v = blockIdx.x * blockDim.x + threadIdx.x;
  if (v >= NN) return;
  nvout[v] = nvin ? nvin[v] : 1;
  scale[v] = 1.0f;
  if (merged) merged[v] = -1;
  for (int j = 0; j < fd; j++) added[(size_t)v * fd + j] = 0.f;
}

__global__ void k_pool_edge(const int* __restrict__ src, const int* __restrict__ dst,
                            const unsigned char* __restrict__ chosen, const float* __restrict__ score,
                            const float* __restrict__ x, unsigned char* __restrict__ nvout,
                            float* __restrict__ scale, float* __restrict__ added,
                            int* __restrict__ merged, int fd) {
  int e = blockIdx.x * blockDim.x + threadIdx.x;
  if (e >= EE) return;
  if (!chosen[e]) return;
  int s = src[e], d = dst[e];
  scale[s] = score[e];
  if (merged) merged[d] = s;
  if (s != d) {
    nvout[d] = 0;
    for (int j = 0; j < fd; j++) added[(size_t)s * fd + j] = x[(size_t)d * fd + j];
  }
}

__global__ void k_newx(const float* __restrict__ x, const float* __restrict__ added,
                       const float* __restrict__ scale, const unsigned char* __restrict__ nvout,
                       float* __restrict__ newx, int fd) {
  int v = blockIdx.x * blockDim.x + threadIdx.x;
  if (v >= NN) return;
  float sc = scale[v];
  int ok = nvout[v];
  for (int j = 0; j < fd; j++)
    newx[(size_t)v * fd + j] =
        ok ? (x[(size_t)v * fd + j] + added[(size_t)v * fd + j]) * sc : 0.f;
}

__global__ void k_cmap(const int* __restrict__ merged, int* __restrict__ cmap) {
  int v = blockIdx.x * blockDim.x + threadIdx.x;
  if (v >= NN) return;
  int m = merged[v];
  cmap[v] = m >= 0 ? m : v;
}

__global__ void k_remap(const int* __restrict__ src, const int* __restrict__ dst,
                        const int* __restrict__ cmap, int* __restrict__ ns, int* __restrict__ nd) {
  int e = blockIdx.x * blockDim.x + threadIdx.x;
  if (e >= EE) return;
  ns[e] = cmap[src[e]];
  nd[e] = cmap[dst[e]];
}

// ---------- dedup via hash: keep min original index per (ns,nd) ----------
__device__ __forceinline__ unsigned int ht_hash(unsigned long long key) {
  return (unsigned int)((key * 0x9E3779B97F4A7C15ULL) >> 44) & HT_MASK;
}

__global__ void k_dedup_ins(const int* __restrict__ ns, const int* __restrict__ nd,
                            unsigned long long* __restrict__ htab) {
  int e = blockIdx.x * blockDim.x + threadIdx.x;
  if (e >= EE) return;
  unsigned long long key =
      (unsigned long long)((((unsigned int)ns[e]) << 16) | (unsigned int)nd[e]);
  unsigned long long val = (key << 32) | (unsigned int)e;
  unsigned int h = ht_hash(key);
  for (;;) {
    unsigned long long curv = htab[h];
    if (curv == ~0ULL) {
      unsigned long long prev = atomicCAS(&htab[h], ~0ULL, val);
      if (prev == ~0ULL) break;
      curv = prev;
    }
    if ((curv >> 32) == key) {
      atomicMin(&htab[h], val);
      break;
    }
    h = (h + 1) & HT_MASK;
  }
}

__global__ void k_dedup_mark(const int* __restrict__ ns, const int* __restrict__ nd,
                             const unsigned long long* __restrict__ htab,
                             unsigned char* __restrict__ evout) {
  int e = blockIdx.x * blockDim.x + threadIdx.x;
  if (e >= EE) return;
  unsigned long long key =
      (unsigned long long)((((unsigned int)ns[e]) << 16) | (unsigned int)nd[e]);
  unsigned int h = ht_hash(key);
  for (;;) {
    unsigned long long curv = htab[h];
    if ((curv >> 32) == key) {
      evout[e] = ((curv & 0xFFFFFFFFULL) == (unsigned long long)(unsigned int)e) ? 1 : 0;
      return;
    }
    h = (h + 1) & HT_MASK;
  }
}

// ---------- readout ----------
__global__ void k_graphpool(const float* __restrict__ h, const unsigned char* __restrict__ nv,
                            const int* __restrict__ batch, float* __restrict__ gsum,
                            float* __restrict__ gcnt) {
  int v = blockIdx.x * blockDim.x + threadIdx.x;
  int lane = threadIdx.x & 63;
  int vc = v < NN ? v : NN - 1;
  int b = batch[vc];
  int active = (v < NN) && nv[v];
  float cnt = active ? 1.f : 0.f;
  float val[CC];
  for (int j = 0; j < CC; j++) val[j] = active ? h[(size_t)v * CC + j] : 0.f;
  int b0 = __shfl(b, 0, 64);
  unsigned long long same = __ballot(b == b0);
  if (same == ~0ULL) {
    for (int o = 32; o > 0; o >>= 1) {
      cnt += __shfl_down(cnt, o, 64);
      for (int j = 0; j < CC; j++) val[j] += __shfl_down(val[j], o, 64);
    }
    if (lane == 0 && cnt > 0.f) {
      atomicAdd(&gcnt[b0], cnt);
      for (int j = 0; j < CC; j++) atomicAdd(&gsum[b0 * CC + j], val[j]);
    }
  } else if (active) {
    atomicAdd(&gcnt[b], cnt);
    for (int j = 0; j < CC; j++) atomicAdd(&gsum[b * CC + j], val[j]);
  }
}

__global__ void k_logsm(const float* __restrict__ gsum, const float* __restrict__ gcnt,
                        float* __restrict__ out) {
  int t = threadIdx.x;
  if (t >= BB) return;
  float gr[CC];
  float c = gcnt[t];
  float m = -INFINITY;
  for (int j = 0; j < CC; j++) {
    gr[j] = gsum[t * CC + j] / c;
    m = fmaxf(m, gr[j]);
  }
  float s = 0.f;
  for (int j = 0; j < CC; j++) s += expf(gr[j] - m);
  float l = logf(s);
  for (int j = 0; j < CC; j++) out[t * CC + j] = gr[j] - m - l;
}

// ---------- host ----------
extern "C" void kernel_launch(void* const* d_in, const int* in_sizes, int n_in,
                              void* d_out, int out_size, void* d_ws, size_t ws_size,
                              hipStream_t stream) {
  const float* x = (const float*)d_in[0];
  const int* src = (const int*)d_in[1];
  const int* dst = (const int*)d_in[2];
  const int* batch = (const int*)d_in[3];
  const float* W1 = (const float*)d_in[4];
  const float* b1 = (const float*)d_in[5];
  const float* W2 = (const float*)d_in[6];
  const float* b2 = (const float*)d_in[7];
  const float* Wp1 = (const float*)d_in[8];
  const float* bp1 = (const float*)d_in[9];
  const float* Wp2 = (const float*)d_in[10];
  const float* bp2 = (const float*)d_in[11];
  float* out = (float*)d_out;

  char* wsb = (char*)d_ws;
  size_t off = 0;
  auto A = [&](size_t bytes) -> char* {
    char* r = wsb + off;
    off = (off + bytes + 255) & ~(size_t)255;
    return r;
  };
  float* h1pre = (float*)A((size_t)NN * HH * 4);
  float* h1out = (float*)A((size_t)NN * HH * 4);
  float* deg = (float*)A((size_t)NN * 4);
  float* dinv = (float*)A((size_t)NN * 4);
  unsigned char* hasloop = (unsigned char*)A(NN);
  unsigned char* addloop = (unsigned char*)A(NN);
  float* raw = (float*)A((size_t)EE * 4);
  float* ex = (float*)A((size_t)EE * 4);
  float* score = (float*)A((size_t)EE * 4);
  unsigned int* mEnc = (unsigned int*)A((size_t)NN * 4);
  float* ssum = (float*)A((size_t)NN * 4);
  unsigned char* chosen = (unsigned char*)A(EE);
  unsigned char* nv1 = (unsigned char*)A(NN);
  unsigned char* nv2 = (unsigned char*)A(NN);
  float* scale = (float*)A((size_t)NN * 4);
  float* added = (float*)A((size_t)NN * CC * 4);
  float* newx1 = (float*)A((size_t)NN * HH * 4);
  int* merged = (int*)A((size_t)NN * 4);
  int* cmap = (int*)A((size_t)NN * 4);
  int* ns = (int*)A((size_t)EE * 4);
  int* nd = (int*)A((size_t)EE * 4);
  unsigned char* ev1 = (unsigned char*)A(EE);
  unsigned long long* htab = (unsigned long long*)A((size_t)HT_SIZE * 8);
  float* h2pre = (float*)A((size_t)NN * CC * 4);
  float* h2out = (float*)A((size_t)NN * CC * 4);
  float* newx2 = (float*)A((size_t)NN * CC * 4);
  ulonglong2* recsB = (ulonglong2*)A((size_t)BB * CAP * 16);
  ulonglong2* scrA = (ulonglong2*)A((size_t)BB * CAP * 16);
  ulonglong2* scrB = (ulonglong2*)A((size_t)BB * CAP * 16);
  int* cnt = (int*)A((size_t)BB * NBANDS * CPAD * 4);
  int* cursors = (int*)A((size_t)BB * NBANDS * CPAD * 4);
  int* bandoff = (int*)A((size_t)BB * NBANDS * 4);
  float* gsum = (float*)A((size_t)BB * CC * 4);
  float* gcnt = (float*)A((size_t)BB * 4);
  (void)ws_size; (void)n_in; (void)in_sizes; (void)out_size;

  const int GE = ngrid(EE), GN = ngrid(NN);

  // ===== stage 1: GCNConv(384->6) + ReLU =====
  hipLaunchKernelGGL(k_mm1, dim3((NN + 3) / 4), dim3(TPB), 0, stream, x, W1, h1pre);
  hipLaunchKernelGGL(k_prep, dim3(GN), dim3(TPB), 0, stream, deg, hasloop, mEnc, ssum, h1out, HH, cnt, gsum, gcnt);
  hipLaunchKernelGGL(k_deg, dim3(GE), dim3(TPB), 0, stream, src, dst, (const unsigned char*)nullptr, deg, hasloop);
  hipLaunchKernelGGL(k_dinv, dim3(GN), dim3(TPB), 0, stream, deg, hasloop, (const unsigned char*)nullptr, dinv, addloop);
  hipLaunchKernelGGL(k_gcn_agg, dim3(GE), dim3(TPB), 0, stream, src, dst, (const unsigned char*)nullptr, dinv, h1pre, h1out, HH);
  hipLaunchKernelGGL(k_gcn_fin, dim3(GN), dim3(TPB), 0, stream, h1pre, dinv, addloop, b1, h1out, HH, 1);

  // ===== edge pool 1 =====
  hipLaunchKernelGGL(k_raw, dim3(GE), dim3(TPB), 0, stream, h1out, src, dst, (const unsigned char*)nullptr, Wp1, bp1, raw, mEnc, HH);
  hipLaunchKernelGGL(k_exps, dim3(GE), dim3(TPB), 0, stream, raw, dst, (const unsigned char*)nullptr, mEnc, ex, ssum);
  hipLaunchKernelGGL(k_score, dim3(GE), dim3(TPB), 0, stream, ex, dst, (const unsigned char*)nullptr, ssum, score, cnt);
  hipLaunchKernelGGL(k_scan, dim3(1), dim3(64), 0, stream, cnt, bandoff, cursors);
  hipLaunchKernelGGL(k_part, dim3(GE), dim3(TPB), 0, stream, src, dst, score, (const unsigned char*)nullptr, recsB, cursors, chosen);
  hipLaunchKernelGGL(k_match_g, dim3(BB), dim3(1024), 0, stream, recsB, scrA, scrB, cnt, bandoff, (const unsigned char*)nullptr, chosen);
  hipLaunchKernelGGL(k_pool_node, dim3(GN), dim3(TPB), 0, stream, (const unsigned char*)nullptr, nv1, scale, merged, added, HH);
  hipLaunchKernelGGL(k_pool_edge, dim3(GE), dim3(TPB), 0, stream, src, dst, chosen, score, h1out, nv1, scale, added, merged, HH);
  hipLaunchKernelGGL(k_newx, dim3(GN), dim3(TPB), 0, stream, h1out, added, scale, nv1, newx1, HH);
  hipLaunchKernelGGL(k_cmap, dim3(GN), dim3(TPB), 0, stream, merged, cmap);
  hipLaunchKernelGGL(k_remap, dim3(GE), dim3(TPB), 0, stream, src, dst, cmap, ns, nd);
  hipMemsetAsync(htab, 0xFF, (size_t)HT_SIZE * 8, stream);
  hipLaunchKernelGGL(k_dedup_ins, dim3(GE), dim3(TPB), 0, stream, ns, nd, htab);
  hipLaunchKernelGGL(k_dedup_mark, dim3(GE), dim3(TPB), 0, stream, ns, nd, htab, ev1);

  // ===== stage 2: GCNConv(6->10) =====
  hipLaunchKernelGGL(k_mm2, dim3(GN), dim3(TPB), 0, stream, newx1, W2, h2pre);
  hipLaunchKernelGGL(k_prep, dim3(GN), dim3(TPB), 0, stream, deg, hasloop, mEnc, ssum, h2out, CC, cnt, gsum, gcnt);
  hipLaunchKernelGGL(k_deg, dim3(GE), dim3(TPB), 0, stream, ns, nd, (const unsigned char*)ev1, deg, hasloop);
  hipLaunchKernelGGL(k_dinv, dim3(GN), dim3(TPB), 0, stream, deg, hasloop, (const unsigned char*)nv1, dinv, addloop);
  hipLaunchKernelGGL(k_gcn_agg, dim3(GE), dim3(TPB), 0, stream, ns, nd, (const unsigned char*)ev1, dinv, h2pre, h2out, CC);
  hipLaunchKernelGGL(k_gcn_fin, dim3(GN), dim3(TPB), 0, stream, h2pre, dinv, addloop, b2, h2out, CC, 0);

  // ===== edge pool 2 =====
  hipLaunchKernelGGL(k_raw, dim3(GE), dim3(TPB), 0, stream, h2out, ns, nd, (const unsigned char*)ev1, Wp2, bp2, raw, mEnc, CC);
  hipLaunchKernelGGL(k_exps, dim3(GE), dim3(TPB), 0, stream, raw, nd, (const unsigned char*)ev1, mEnc, ex, ssum);
  hipLaunchKernelGGL(k_score, dim3(GE), dim3(TPB), 0, stream, ex, nd, (const unsigned char*)ev1, ssum, score, cnt);
  hipLaunchKernelGGL(k_scan, dim3(1), dim3(64), 0, stream, cnt, bandoff, cursors);
  hipLaunchKernelGGL(k_part, dim3(GE), dim3(TPB), 0, stream, ns, nd, score, (const unsigned char*)ev1, recsB, cursors, chosen);
  hipLaunchKernelGGL(k_match_g, dim3(BB), dim3(1024), 0, stream, recsB, scrA, scrB, cnt, bandoff, (const unsigned char*)nv1, chosen);
  hipLaunchKernelGGL(k_pool_node, dim3(GN), dim3(TPB), 0, stream, (const unsigned char*)nv1, nv2, scale, (int*)nullptr, added, CC);
  hipLaunchKernelGGL(k_pool_edge, dim3(GE), dim3(TPB), 0, stream, ns, nd, chosen, score, h2out, nv2, scale, added, (int*)nullptr, CC);
  hipLaunchKernelGGL(k_newx, dim3(GN), dim3(TPB), 0, stream, h2out, added, scale, nv2, newx2, CC);

  // ===== readout =====
  hipLaunchKernelGGL(k_graphpool, dim3(GN), dim3(TPB), 0, stream, newx2, nv2, batch, gsum, gcnt);
  hipLaunchKernelGGL(k_logsm, dim3(1), dim3(64), 0, stream, gsum, gcnt, out);
}

// Round 6
// 2110.649 us; speedup vs baseline: 2.5744x; 2.5744x over previous
//
#include <hip/hip_runtime.h>
#include <math.h>

#define NN 60000
#define BB 8
#define GS 7500   // nodes per graph
#define FF 384
#define EE 600000
#define HH 6
#define CC 10
#define HT_BITS 20
#define HT_SIZE (1u << HT_BITS)
#define HT_MASK (HT_SIZE - 1u)
#define TPB 256
#define CAP 80000  // per-graph edge capacity (mean 75000)
#define REMW ((GS + 31) / 32)
#define GPAD 32    // gcnts padding: one counter per 128B (R3 lesson)

static inline int ngrid(int n) { return (n + TPB - 1) / TPB; }

// ---------- helpers ----------
__device__ __forceinline__ unsigned int encf(float v) {
  unsigned int b = __float_as_uint(v);
  return (b & 0x80000000u) ? ~b : (b | 0x80000000u);
}
__device__ __forceinline__ float decf(unsigned int u) {
  unsigned int b = (u & 0x80000000u) ? (u & 0x7FFFFFFFu) : ~u;
  return __uint_as_float(b);
}

// ---------- stage 1 matmul: h1pre = x @ W1 (N x 384 @ 384 x 6) ----------
__global__ void k_mm1(const float* __restrict__ x, const float* __restrict__ W,
                      float* __restrict__ out) {
  __shared__ float Ws[FF * HH];
  for (int i = threadIdx.x; i < FF * HH; i += blockDim.x) Ws[i] = W[i];
  __syncthreads();
  int wave = threadIdx.x >> 6, lane = threadIdx.x & 63;
  int node = blockIdx.x * 4 + wave;
  if (node >= NN) return;
  const float* xr = x + (size_t)node * FF;
  float acc[HH] = {0.f, 0.f, 0.f, 0.f, 0.f, 0.f};
  for (int k = lane; k < FF; k += 64) {
    float xv = xr[k];
#pragma unroll
    for (int j = 0; j < HH; j++) acc[j] += xv * Ws[k * HH + j];
  }
#pragma unroll
  for (int j = 0; j < HH; j++) {
#pragma unroll
    for (int o = 32; o > 0; o >>= 1) acc[j] += __shfl_down(acc[j], o, 64);
  }
  if (lane == 0) {
#pragma unroll
    for (int j = 0; j < HH; j++) out[(size_t)node * HH + j] = acc[j];
  }
}

// ---------- stage 2 matmul ----------
__global__ void k_mm2(const float* __restrict__ x, const float* __restrict__ W,
                      float* __restrict__ out) {
  int v = blockIdx.x * blockDim.x + threadIdx.x;
  if (v >= NN) return;
  float xv[HH];
#pragma unroll
  for (int j = 0; j < HH; j++) xv[j] = x[(size_t)v * HH + j];
#pragma unroll
  for (int c = 0; c < CC; c++) {
    float a = 0.f;
#pragma unroll
    for (int j = 0; j < HH; j++) a += xv[j] * W[j * CC + c];
    out[(size_t)v * CC + c] = a;
  }
}

// ---------- fused per-stage init (replaces memsets + old k_pool_node) ----------
__global__ void k_prep(float* __restrict__ deg, unsigned char* __restrict__ hasloop,
                       unsigned int* __restrict__ mEnc, float* __restrict__ ssum,
                       float* __restrict__ hout, int fd, int* __restrict__ gcnts,
                       float* __restrict__ gsum, float* __restrict__ gcnt,
                       const unsigned char* __restrict__ nvin, unsigned char* __restrict__ nvout,
                       float* __restrict__ scale, int* __restrict__ merged,
                       float* __restrict__ added) {
  int v = blockIdx.x * blockDim.x + threadIdx.x;
  if (v >= NN) return;
  deg[v] = 0.f;
  hasloop[v] = 0;
  mEnc[v] = 0;
  ssum[v] = 0.f;
  for (int j = 0; j < fd; j++) hout[(size_t)v * fd + j] = 0.f;
  nvout[v] = nvin ? nvin[v] : 1;
  scale[v] = 1.0f;
  if (merged) merged[v] = -1;
  for (int j = 0; j < fd; j++) added[(size_t)v * fd + j] = 0.f;
  if (v < BB * GPAD) gcnts[v] = 0;
  if (v < BB * CC) gsum[v] = 0.f;
  if (v < BB) gcnt[v] = 0.f;
}

// ---------- generic GCN conv pieces ----------
__global__ void k_deg(const int* __restrict__ src, const int* __restrict__ dst,
                      const unsigned char* __restrict__ ev, float* __restrict__ deg,
                      unsigned char* __restrict__ hasloop) {
  int e = blockIdx.x * blockDim.x + threadIdx.x;
  if (e >= EE) return;
  if (ev && !ev[e]) return;
  int d = dst[e];
  atomicAdd(&deg[d], 1.0f);
  if (src[e] == d) hasloop[d] = 1;
}

__global__ void k_dinv(const float* __restrict__ deg, const unsigned char* __restrict__ hasloop,
                       const unsigned char* __restrict__ nv, float* __restrict__ dinv,
                       unsigned char* __restrict__ addloop) {
  int v = blockIdx.x * blockDim.x + threadIdx.x;
  if (v >= NN) return;
  int nvv = nv ? (int)nv[v] : 1;
  unsigned char al = (nvv && !hasloop[v]) ? 1 : 0;
  float d = deg[v] + (float)al;
  dinv[v] = d > 0.f ? 1.0f / sqrtf(fmaxf(d, 1e-12f)) : 0.f;
  addloop[v] = al;
}

__global__ void k_gcn_agg(const int* __restrict__ src, const int* __restrict__ dst,
                          const unsigned char* __restrict__ ev, const float* __restrict__ dinv,
                          const float* __restrict__ h, float* __restrict__ out, int fd) {
  int e = blockIdx.x * blockDim.x + threadIdx.x;
  if (e >= EE) return;
  if (ev && !ev[e]) return;
  int s = src[e], d = dst[e];
  float c = dinv[s] * dinv[d];
  for (int j = 0; j < fd; j++)
    atomicAdd(&out[(size_t)d * fd + j], h[(size_t)s * fd + j] * c);
}

__global__ void k_gcn_fin(const float* __restrict__ h, const float* __restrict__ dinv,
                          const unsigned char* __restrict__ addloop, const float* __restrict__ b,
                          float* __restrict__ out, int fd, int relu) {
  int v = blockIdx.x * blockDim.x + threadIdx.x;
  if (v >= NN) return;
  float c = addloop[v] ? dinv[v] * dinv[v] : 0.f;
  for (int j = 0; j < fd; j++) {
    float o = out[(size_t)v * fd + j] + c * h[(size_t)v * fd + j] + b[j];
    if (relu) o = fmaxf(o, 0.f);
    out[(size_t)v * fd + j] = o;
  }
}

// ---------- edge pool: scores ----------
__global__ void k_raw(const float* __restrict__ x, const int* __restrict__ src,
                      const int* __restrict__ dst, const unsigned char* __restrict__ ev,
                      const float* __restrict__ Wp, const float* __restrict__ bp,
                      float* __restrict__ raw, unsigned int* __restrict__ mEnc, int fd) {
  int e = blockIdx.x * blockDim.x + threadIdx.x;
  if (e >= EE) return;
  if (ev && !ev[e]) return;
  int s = src[e], d = dst[e];
  float r = bp[0];
  for (int j = 0; j < fd; j++) r += x[(size_t)s * fd + j] * Wp[j];
  for (int j = 0; j < fd; j++) r += x[(size_t)d * fd + j] * Wp[fd + j];
  raw[e] = r;
  atomicMax(&mEnc[d], encf(r));
}

__global__ void k_exps(const float* __restrict__ raw, const int* __restrict__ dst,
                       const unsigned char* __restrict__ ev, const unsigned int* __restrict__ mEnc,
                       float* __restrict__ ex, float* __restrict__ ssum) {
  int e = blockIdx.x * blockDim.x + threadIdx.x;
  if (e >= EE) return;
  if (ev && !ev[e]) return;
  int d = dst[e];
  unsigned int me = mEnc[d];
  float m = me ? decf(me) : 0.f;
  float v = expf(raw[e] - m);
  ex[e] = v;
  atomicAdd(&ssum[d], v);
}

__global__ void k_score(const float* __restrict__ ex, const int* __restrict__ dst,
                        const unsigned char* __restrict__ ev, const float* __restrict__ ssum,
                        float* __restrict__ score) {
  int e = blockIdx.x * blockDim.x + threadIdx.x;
  if (e >= EE) return;
  if (ev && !ev[e]) return;
  float sd = ssum[dst[e]];
  score[e] = ex[e] / (sd > 0.f ? sd : 1.0f) + 0.5f;
}

// ---------- partition edges by graph; block-aggregated offsets ----------
// record = { prio = score_bits<<32 | ~e , payload = s<<32 | d }
__global__ void k_part(const int* __restrict__ src, const int* __restrict__ dst,
                       const float* __restrict__ score, const unsigned char* __restrict__ ev,
                       ulonglong2* __restrict__ recs, int* __restrict__ gcnts,
                       unsigned char* __restrict__ chosen) {
  __shared__ int wcnt[TPB / 64][BB];
  __shared__ int bbase[BB];
  int e = blockIdx.x * blockDim.x + threadIdx.x;
  int w = threadIdx.x >> 6, lane = threadIdx.x & 63;
  int valid = 0, s = 0, d = 0, g = 0;
  if (e < EE) {
    chosen[e] = 0;
    if (!ev || ev[e]) { valid = 1; s = src[e]; d = dst[e]; g = s / GS; }
  }
  unsigned long long p = 0;
  if (valid)
    p = (((unsigned long long)__float_as_uint(score[e])) << 32) |
        (unsigned int)(~(unsigned int)e);
  int myrank = 0;
#pragma unroll
  for (int gg = 0; gg < BB; gg++) {
    unsigned long long m = __ballot(valid && g == gg);
    if (valid && g == gg) myrank = __popcll(m & ((1ULL << lane) - 1ULL));
    if (lane == 0) wcnt[w][gg] = __popcll(m);
  }
  __syncthreads();
  if (threadIdx.x < BB) {
    int gg = threadIdx.x, tot = 0;
#pragma unroll
    for (int ww = 0; ww < TPB / 64; ww++) {
      int c = wcnt[ww][gg];
      wcnt[ww][gg] = tot;
      tot += c;
    }
    bbase[gg] = tot ? atomicAdd(&gcnts[gg * GPAD], tot) : 0;
  }
  __syncthreads();
  if (valid)
    recs[(size_t)g * CAP + bbase[g] + wcnt[w][g] + myrank] =
        make_ulonglong2(p, (((unsigned long long)(unsigned int)s) << 32) | (unsigned int)d);
}

// ---------- matching: per-graph locally-dominant greedy, all-LDS state ----------
// One block per graph; survivor-driven best[] clearing; read-before-atomic
// (best[] is monotone within a round -> skipping superseded posts is race-safe).
__global__ __launch_bounds__(1024) void k_match_g(ulonglong2* __restrict__ recs0,
                                                  ulonglong2* __restrict__ recs1,
                                                  const int* __restrict__ gcnts,
                                                  const unsigned char* __restrict__ nv,
                                                  unsigned char* __restrict__ chosen) {
  __shared__ unsigned long long best[GS];
  __shared__ unsigned int remB[REMW];
  __shared__ int cnt_next;
  const int g = blockIdx.x;
  const int base = g * GS;
  const int t = threadIdx.x, nth = blockDim.x;
  const int lane = t & 63;

  for (int w = t; w < REMW; w += nth) {
    unsigned int bits = 0;
    for (int b = 0; b < 32; b++) {
      int v = w * 32 + b;
      if (v < GS) bits |= (nv ? (nv[base + v] ? 1u : 0u) : 1u) << b;
    }
    remB[w] = bits;
  }
  for (int i = t; i < GS; i += nth) best[i] = 0ULL;
  __syncthreads();

  ulonglong2* bufs[2] = {recs0 + (size_t)g * CAP, recs1 + (size_t)g * CAP};
  int n = gcnts[g * GPAD];
  int cur = 0;

  while (n > 0) {
    // P1: live edges post priority at both endpoints (read-check then LDS atomicMax)
    for (int i = t; i < n; i += nth) {
      ulonglong2 r = bufs[cur][i];
      int ls = (int)(r.y >> 32) - base, ld = (int)(r.y & 0xFFFFFFFFu) - base;
      if (((remB[ls >> 5] >> (ls & 31)) & 1u) && ((remB[ld >> 5] >> (ld & 31)) & 1u)) {
        if (best[ls] < r.x) atomicMax(&best[ls], r.x);
        if (ld != ls && best[ld] < r.x) atomicMax(&best[ld], r.x);
      }
    }
    if (t == 0) cnt_next = 0;
    __syncthreads();
    // P2: local winners commit; survivors compact into other buffer
    for (int i = t; i < n; i += nth) {
      ulonglong2 r = bufs[cur][i];
      int ls = (int)(r.y >> 32) - base, ld = (int)(r.y & 0xFFFFFFFFu) - base;
      int keep = 0;
      if (((remB[ls >> 5] >> (ls & 31)) & 1u) && ((remB[ld >> 5] >> (ld & 31)) & 1u)) {
        if (best[ls] == r.x && best[ld] == r.x) {
          int e = (int)(~(unsigned int)(r.x & 0xFFFFFFFFu));
          chosen[e] = 1;
          atomicAnd(&remB[ls >> 5], ~(1u << (ls & 31)));
          atomicAnd(&remB[ld >> 5], ~(1u << (ld & 31)));
        } else {
          keep = 1;
        }
      }
      unsigned long long m = __ballot(keep);
      int tot = __popcll(m);
      int pre = __popcll(m & ((1ULL << lane) - 1ULL));
      int b0 = 0;
      if (lane == 0 && tot) b0 = atomicAdd(&cnt_next, tot);
      b0 = __shfl(b0, 0, 64);
      if (keep) bufs[cur ^ 1][b0 + pre] = r;
    }
    __syncthreads();
    n = cnt_next;
    // P3: clear best[] only at surviving edges' endpoints (benign write races)
    for (int i = t; i < n; i += nth) {
      ulonglong2 r = bufs[cur ^ 1][i];
      best[(int)(r.y >> 32) - base] = 0ULL;
      best[(int)(r.y & 0xFFFFFFFFu) - base] = 0ULL;
    }
    __syncthreads();
    cur ^= 1;
  }
}

// ---------- edge pool: post-matching ----------
__global__ void k_pool_edge(const int* __restrict__ src, const int* __restrict__ dst,
                            const unsigned char* __restrict__ chosen, const float* __restrict__ score,
                            const float* __restrict__ x, unsigned char* __restrict__ nvout,
                            float* __restrict__ scale, float* __restrict__ added,
                            int* __restrict__ merged, int fd) {
  int e = blockIdx.x * blockDim.x + threadIdx.x;
  if (e >= EE) return;
  if (!chosen[e]) return;
  int s = src[e], d = dst[e];
  scale[s] = score[e];
  if (merged) merged[d] = s;
  if (s != d) {
    nvout[d] = 0;
    for (int j = 0; j < fd; j++) added[(size_t)s * fd + j] = x[(size_t)d * fd + j];
  }
}

__global__ void k_newx(const float* __restrict__ x, const float* __restrict__ added,
                       const float* __restrict__ scale, const unsigned char* __restrict__ nvout,
                       float* __restrict__ newx, int fd) {
  int v = blockIdx.x * blockDim.x + threadIdx.x;
  if (v >= NN) return;
  float sc = scale[v];
  int ok = nvout[v];
  for (int j = 0; j < fd; j++)
    newx[(size_t)v * fd + j] =
        ok ? (x[(size_t)v * fd + j] + added[(size_t)v * fd + j]) * sc : 0.f;
}

// remap with fused cluster-map (reads merged directly)
__global__ void k_remap(const int* __restrict__ src, const int* __restrict__ dst,
                        const int* __restrict__ merged, int* __restrict__ ns, int* __restrict__ nd) {
  int e = blockIdx.x * blockDim.x + threadIdx.x;
  if (e >= EE) return;
  int s = src[e], d = dst[e];
  int ms = merged[s], md = merged[d];
  ns[e] = ms >= 0 ? ms : s;
  nd[e] = md >= 0 ? md : d;
}

// ---------- dedup via hash: keep min original index per (ns,nd) ----------
__device__ __forceinline__ unsigned int ht_hash(unsigned long long key) {
  return (unsigned int)((key * 0x9E3779B97F4A7C15ULL) >> 44) & HT_MASK;
}

__global__ void k_dedup_ins(const int* __restrict__ ns, const int* __restrict__ nd,
                            unsigned long long* __restrict__ htab) {
  int e = blockIdx.x * blockDim.x + threadIdx.x;
  if (e >= EE) return;
  unsigned long long key =
      (unsigned long long)((((unsigned int)ns[e]) << 16) | (unsigned int)nd[e]);
  unsigned long long val = (key << 32) | (unsigned int)e;
  unsigned int h = ht_hash(key);
  for (;;) {
    unsigned long long curv = htab[h];
    if (curv == ~0ULL) {
      unsigned long long prev = atomicCAS(&htab[h], ~0ULL, val);
      if (prev == ~0ULL) break;
      curv = prev;
    }
    if ((curv >> 32) == key) {
      atomicMin(&htab[h], val);
      break;
    }
    h = (h + 1) & HT_MASK;
  }
}

__global__ void k_dedup_mark(const int* __restrict__ ns, const int* __restrict__ nd,
                             const unsigned long long* __restrict__ htab,
                             unsigned char* __restrict__ evout) {
  int e = blockIdx.x * blockDim.x + threadIdx.x;
  if (e >= EE) return;
  unsigned long long key =
      (unsigned long long)((((unsigned int)ns[e]) << 16) | (unsigned int)nd[e]);
  unsigned int h = ht_hash(key);
  for (;;) {
    unsigned long long curv = htab[h];
    if ((curv >> 32) == key) {
      evout[e] = ((curv & 0xFFFFFFFFULL) == (unsigned long long)(unsigned int)e) ? 1 : 0;
      return;
    }
    h = (h + 1) & HT_MASK;
  }
}

// ---------- readout ----------
__global__ void k_graphpool(const float* __restrict__ h, const unsigned char* __restrict__ nv,
                            const int* __restrict__ batch, float* __restrict__ gsum,
                            float* __restrict__ gcnt) {
  int v = blockIdx.x * blockDim.x + threadIdx.x;
  int lane = threadIdx.x & 63;
  int vc = v < NN ? v : NN - 1;
  int b = batch[vc];
  int active = (v < NN) && nv[v];
  float cnt = active ? 1.f : 0.f;
  float val[CC];
  for (int j = 0; j < CC; j++) val[j] = active ? h[(size_t)v * CC + j] : 0.f;
  int b0 = __shfl(b, 0, 64);
  unsigned long long same = __ballot(b == b0);
  if (same == ~0ULL) {
    for (int o = 32; o > 0; o >>= 1) {
      cnt += __shfl_down(cnt, o, 64);
      for (int j = 0; j < CC; j++) val[j] += __shfl_down(val[j], o, 64);
    }
    if (lane == 0 && cnt > 0.f) {
      atomicAdd(&gcnt[b0], cnt);
      for (int j = 0; j < CC; j++) atomicAdd(&gsum[b0 * CC + j], val[j]);
    }
  } else if (active) {
    atomicAdd(&gcnt[b], cnt);
    for (int j = 0; j < CC; j++) atomicAdd(&gsum[b * CC + j], val[j]);
  }
}

__global__ void k_logsm(const float* __restrict__ gsum, const float* __restrict__ gcnt,
                        float* __restrict__ out) {
  int t = threadIdx.x;
  if (t >= BB) return;
  float gr[CC];
  float c = gcnt[t];
  float m = -INFINITY;
  for (int j = 0; j < CC; j++) {
    gr[j] = gsum[t * CC + j] / c;
    m = fmaxf(m, gr[j]);
  }
  float s = 0.f;
  for (int j = 0; j < CC; j++) s += expf(gr[j] - m);
  float l = logf(s);
  for (int j = 0; j < CC; j++) out[t * CC + j] = gr[j] - m - l;
}

// ---------- host ----------
extern "C" void kernel_launch(void* const* d_in, const int* in_sizes, int n_in,
                              void* d_out, int out_size, void* d_ws, size_t ws_size,
                              hipStream_t stream) {
  const float* x = (const float*)d_in[0];
  const int* src = (const int*)d_in[1];
  const int* dst = (const int*)d_in[2];
  const int* batch = (const int*)d_in[3];
  const float* W1 = (const float*)d_in[4];
  const float* b1 = (const float*)d_in[5];
  const float* W2 = (const float*)d_in[6];
  const float* b2 = (const float*)d_in[7];
  const float* Wp1 = (const float*)d_in[8];
  const float* bp1 = (const float*)d_in[9];
  const float* Wp2 = (const float*)d_in[10];
  const float* bp2 = (const float*)d_in[11];
  float* out = (float*)d_out;

  char* wsb = (char*)d_ws;
  size_t off = 0;
  auto A = [&](size_t bytes) -> char* {
    char* r = wsb + off;
    off = (off + bytes + 255) & ~(size_t)255;
    return r;
  };
  float* h1pre = (float*)A((size_t)NN * HH * 4);
  float* h1out = (float*)A((size_t)NN * HH * 4);
  float* deg = (float*)A((size_t)NN * 4);
  float* dinv = (float*)A((size_t)NN * 4);
  unsigned char* hasloop = (unsigned char*)A(NN);
  unsigned char* addloop = (unsigned char*)A(NN);
  float* raw = (float*)A((size_t)EE * 4);
  float* ex = (float*)A((size_t)EE * 4);
  float* score = (float*)A((size_t)EE * 4);
  unsigned int* mEnc = (unsigned int*)A((size_t)NN * 4);
  float* ssum = (float*)A((size_t)NN * 4);
  unsigned char* chosen = (unsigned char*)A(EE);
  unsigned char* nv1 = (unsigned char*)A(NN);
  unsigned char* nv2 = (unsigned char*)A(NN);
  float* scale = (float*)A((size_t)NN * 4);
  float* added = (float*)A((size_t)NN * CC * 4);
  float* newx1 = (float*)A((size_t)NN * HH * 4);
  int* merged = (int*)A((size_t)NN * 4);
  int* ns = (int*)A((size_t)EE * 4);
  int* nd = (int*)A((size_t)EE * 4);
  unsigned char* ev1 = (unsigned char*)A(EE);
  unsigned long long* htab = (unsigned long long*)A((size_t)HT_SIZE * 8);
  float* h2pre = (float*)A((size_t)NN * CC * 4);
  float* h2out = (float*)A((size_t)NN * CC * 4);
  float* newx2 = (float*)A((size_t)NN * CC * 4);
  ulonglong2* recs0 = (ulonglong2*)A((size_t)BB * CAP * 16);
  ulonglong2* recs1 = (ulonglong2*)A((size_t)BB * CAP * 16);
  int* gcnts = (int*)A((size_t)BB * GPAD * 4);
  float* gsum = (float*)A((size_t)BB * CC * 4);
  float* gcnt = (float*)A((size_t)BB * 4);
  (void)ws_size; (void)n_in; (void)in_sizes; (void)out_size;

  const int GE = ngrid(EE), GN = ngrid(NN);

  // ===== stage 1: GCNConv(384->6) + ReLU =====
  hipLaunchKernelGGL(k_mm1, dim3((NN + 3) / 4), dim3(TPB), 0, stream, x, W1, h1pre);
  hipLaunchKernelGGL(k_prep, dim3(GN), dim3(TPB), 0, stream, deg, hasloop, mEnc, ssum, h1out, HH, gcnts, gsum, gcnt,
                     (const unsigned char*)nullptr, nv1, scale, merged, added);
  hipLaunchKernelGGL(k_deg, dim3(GE), dim3(TPB), 0, stream, src, dst, (const unsigned char*)nullptr, deg, hasloop);
  hipLaunchKernelGGL(k_dinv, dim3(GN), dim3(TPB), 0, stream, deg, hasloop, (const unsigned char*)nullptr, dinv, addloop);
  hipLaunchKernelGGL(k_gcn_agg, dim3(GE), dim3(TPB), 0, stream, src, dst, (const unsigned char*)nullptr, dinv, h1pre, h1out, HH);
  hipLaunchKernelGGL(k_gcn_fin, dim3(GN), dim3(TPB), 0, stream, h1pre, dinv, addloop, b1, h1out, HH, 1);

  // ===== edge pool 1 =====
  hipLaunchKernelGGL(k_raw, dim3(GE), dim3(TPB), 0, stream, h1out, src, dst, (const unsigned char*)nullptr, Wp1, bp1, raw, mEnc, HH);
  hipLaunchKernelGGL(k_exps, dim3(GE), dim3(TPB), 0, stream, raw, dst, (const unsigned char*)nullptr, mEnc, ex, ssum);
  hipLaunchKernelGGL(k_score, dim3(GE), dim3(TPB), 0, stream, ex, dst, (const unsigned char*)nullptr, ssum, score);
  hipLaunchKernelGGL(k_part, dim3(GE), dim3(TPB), 0, stream, src, dst, score, (const unsigned char*)nullptr, recs0, gcnts, chosen);
  hipLaunchKernelGGL(k_match_g, dim3(BB), dim3(1024), 0, stream, recs0, recs1, gcnts, (const unsigned char*)nullptr, chosen);
  hipLaunchKernelGGL(k_pool_edge, dim3(GE), dim3(TPB), 0, stream, src, dst, chosen, score, h1out, nv1, scale, added, merged, HH);
  hipLaunchKernelGGL(k_newx, dim3(GN), dim3(TPB), 0, stream, h1out, added, scale, nv1, newx1, HH);
  hipLaunchKernelGGL(k_remap, dim3(GE), dim3(TPB), 0, stream, src, dst, merged, ns, nd);
  hipMemsetAsync(htab, 0xFF, (size_t)HT_SIZE * 8, stream);
  hipLaunchKernelGGL(k_dedup_ins, dim3(GE), dim3(TPB), 0, stream, ns, nd, htab);
  hipLaunchKernelGGL(k_dedup_mark, dim3(GE), dim3(TPB), 0, stream, ns, nd, htab, ev1);

  // ===== stage 2: GCNConv(6->10) =====
  hipLaunchKernelGGL(k_mm2, dim3(GN), dim3(TPB), 0, stream, newx1, W2, h2pre);
  hipLaunchKernelGGL(k_prep, dim3(GN), dim3(TPB), 0, stream, deg, hasloop, mEnc, ssum, h2out, CC, gcnts, gsum, gcnt,
                     (const unsigned char*)nv1, nv2, scale, (int*)nullptr, added);
  hipLaunchKernelGGL(k_deg, dim3(GE), dim3(TPB), 0, stream, ns, nd, (const unsigned char*)ev1, deg, hasloop);
  hipLaunchKernelGGL(k_dinv, dim3(GN), dim3(TPB), 0, stream, deg, hasloop, (const unsigned char*)nv1, dinv, addloop);
  hipLaunchKernelGGL(k_gcn_agg, dim3(GE), dim3(TPB), 0, stream, ns, nd, (const unsigned char*)ev1, dinv, h2pre, h2out, CC);
  hipLaunchKernelGGL(k_gcn_fin, dim3(GN), dim3(TPB), 0, stream, h2pre, dinv, addloop, b2, h2out, CC, 0);

  // ===== edge pool 2 =====
  hipLaunchKernelGGL(k_raw, dim3(GE), dim3(TPB), 0, stream, h2out, ns, nd, (const unsigned char*)ev1, Wp2, bp2, raw, mEnc, CC);
  hipLaunchKernelGGL(k_exps, dim3(GE), dim3(TPB), 0, stream, raw, nd, (const unsigned char*)ev1, mEnc, ex, ssum);
  hipLaunchKernelGGL(k_score, dim3(GE), dim3(TPB), 0, stream, ex, nd, (const unsigned char*)ev1, ssum, score);
  hipLaunchKernelGGL(k_part, dim3(GE), dim3(TPB), 0, stream, ns, nd, score, (const unsigned char*)ev1, recs0, gcnts, chosen);
  hipLaunchKernelGGL(k_match_g, dim3(BB), dim3(1024), 0, stream, recs0, recs1, gcnts, (const unsigned char*)nv1, chosen);
  hipLaunchKernelGGL(k_pool_edge, dim3(GE), dim3(TPB), 0, stream, ns, nd, chosen, score, h2out, nv2, scale, added, (int*)nullptr, CC);
  hipLaunchKernelGGL(k_newx, dim3(GN), dim3(TPB), 0, stream, h2out, added, scale, nv2, newx2, CC);

  // ===== readout =====
  hipLaunchKernelGGL(k_graphpool, dim3(GN), dim3(TPB), 0, stream, newx2, nv2, batch, gsum, gcnt);
  hipLaunchKernelGGL(k_logsm, dim3(1), dim3(64), 0, stream, gsum, gcnt, out);
}

// Round 7
// 2017.959 us; speedup vs baseline: 2.6927x; 1.0459x over previous
//
#include <hip/hip_runtime.h>
#include <math.h>

#define NN 60000
#define BB 8
#define GS 7500   // nodes per graph
#define FF 384
#define EE 600000
#define HH 6
#define CC 10
#define HT_BITS 20
#define HT_SIZE (1u << HT_BITS)
#define HT_MASK (HT_SIZE - 1u)
#define TPB 256
#define CAP 80000  // per-graph edge capacity (mean 75000)
#define REMW ((GS + 31) / 32)
#define GPAD 32    // gcnts padding: one counter per 128B (R3 lesson)

static inline int ngrid(int n) { return (n + TPB - 1) / TPB; }

// ---------- helpers ----------
__device__ __forceinline__ unsigned int encf(float v) {
  unsigned int b = __float_as_uint(v);
  return (b & 0x80000000u) ? ~b : (b | 0x80000000u);
}
__device__ __forceinline__ float decf(unsigned int u) {
  unsigned int b = (u & 0x80000000u) ? (u & 0x7FFFFFFFu) : ~u;
  return __uint_as_float(b);
}

// ---------- stage 1 matmul: h1pre = x @ W1 (N x 384 @ 384 x 6) ----------
__global__ void k_mm1(const float* __restrict__ x, const float* __restrict__ W,
                      float* __restrict__ out) {
  __shared__ float Ws[FF * HH];
  for (int i = threadIdx.x; i < FF * HH; i += blockDim.x) Ws[i] = W[i];
  __syncthreads();
  int wave = threadIdx.x >> 6, lane = threadIdx.x & 63;
  int node = blockIdx.x * 4 + wave;
  if (node >= NN) return;
  const float* xr = x + (size_t)node * FF;
  float acc[HH] = {0.f, 0.f, 0.f, 0.f, 0.f, 0.f};
  for (int k = lane; k < FF; k += 64) {
    float xv = xr[k];
#pragma unroll
    for (int j = 0; j < HH; j++) acc[j] += xv * Ws[k * HH + j];
  }
#pragma unroll
  for (int j = 0; j < HH; j++) {
#pragma unroll
    for (int o = 32; o > 0; o >>= 1) acc[j] += __shfl_down(acc[j], o, 64);
  }
  if (lane == 0) {
#pragma unroll
    for (int j = 0; j < HH; j++) out[(size_t)node * HH + j] = acc[j];
  }
}

// ---------- stage 2 matmul ----------
__global__ void k_mm2(const float* __restrict__ x, const float* __restrict__ W,
                      float* __restrict__ out) {
  int v = blockIdx.x * blockDim.x + threadIdx.x;
  if (v >= NN) return;
  float xv[HH];
#pragma unroll
  for (int j = 0; j < HH; j++) xv[j] = x[(size_t)v * HH + j];
#pragma unroll
  for (int c = 0; c < CC; c++) {
    float a = 0.f;
#pragma unroll
    for (int j = 0; j < HH; j++) a += xv[j] * W[j * CC + c];
    out[(size_t)v * CC + c] = a;
  }
}

// ---------- fused per-stage init ----------
__global__ void k_prep(float* __restrict__ deg, unsigned char* __restrict__ hasloop,
                       unsigned int* __restrict__ mEnc, float* __restrict__ ssum,
                       float* __restrict__ hout, int fd, int* __restrict__ gcnts,
                       float* __restrict__ gsum, float* __restrict__ gcnt,
                       const unsigned char* __restrict__ nvin, unsigned char* __restrict__ nvout,
                       float* __restrict__ scale, int* __restrict__ merged,
                       int* __restrict__ partner) {
  int v = blockIdx.x * blockDim.x + threadIdx.x;
  if (v >= NN) return;
  deg[v] = 0.f;
  hasloop[v] = 0;
  mEnc[v] = 0;
  ssum[v] = 0.f;
  for (int j = 0; j < fd; j++) hout[(size_t)v * fd + j] = 0.f;
  nvout[v] = nvin ? nvin[v] : 1;
  scale[v] = 1.0f;
  if (merged) merged[v] = -1;
  partner[v] = -1;
  if (v < BB * GPAD) gcnts[v] = 0;
  if (v < BB * CC) gsum[v] = 0.f;
  if (v < BB) gcnt[v] = 0.f;
}

// ---------- generic GCN conv pieces ----------
__global__ void k_deg(const int* __restrict__ src, const int* __restrict__ dst,
                      const unsigned char* __restrict__ ev, float* __restrict__ deg,
                      unsigned char* __restrict__ hasloop) {
  int e = blockIdx.x * blockDim.x + threadIdx.x;
  if (e >= EE) return;
  if (ev && !ev[e]) return;
  int d = dst[e];
  atomicAdd(&deg[d], 1.0f);
  if (src[e] == d) hasloop[d] = 1;
}

__global__ void k_dinv(const float* __restrict__ deg, const unsigned char* __restrict__ hasloop,
                       const unsigned char* __restrict__ nv, float* __restrict__ dinv,
                       unsigned char* __restrict__ addloop) {
  int v = blockIdx.x * blockDim.x + threadIdx.x;
  if (v >= NN) return;
  int nvv = nv ? (int)nv[v] : 1;
  unsigned char al = (nvv && !hasloop[v]) ? 1 : 0;
  float d = deg[v] + (float)al;
  dinv[v] = d > 0.f ? 1.0f / sqrtf(fmaxf(d, 1e-12f)) : 0.f;
  addloop[v] = al;
}

__global__ void k_gcn_agg(const int* __restrict__ src, const int* __restrict__ dst,
                          const unsigned char* __restrict__ ev, const float* __restrict__ dinv,
                          const float* __restrict__ h, float* __restrict__ out, int fd) {
  int e = blockIdx.x * blockDim.x + threadIdx.x;
  if (e >= EE) return;
  if (ev && !ev[e]) return;
  int s = src[e], d = dst[e];
  float c = dinv[s] * dinv[d];
  for (int j = 0; j < fd; j++)
    atomicAdd(&out[(size_t)d * fd + j], h[(size_t)s * fd + j] * c);
}

__global__ void k_gcn_fin(const float* __restrict__ h, const float* __restrict__ dinv,
                          const unsigned char* __restrict__ addloop, const float* __restrict__ b,
                          float* __restrict__ out, int fd, int relu) {
  int v = blockIdx.x * blockDim.x + threadIdx.x;
  if (v >= NN) return;
  float c = addloop[v] ? dinv[v] * dinv[v] : 0.f;
  for (int j = 0; j < fd; j++) {
    float o = out[(size_t)v * fd + j] + c * h[(size_t)v * fd + j] + b[j];
    if (relu) o = fmaxf(o, 0.f);
    out[(size_t)v * fd + j] = o;
  }
}

// ---------- edge pool: scores ----------
__global__ void k_raw(const float* __restrict__ x, const int* __restrict__ src,
                      const int* __restrict__ dst, const unsigned char* __restrict__ ev,
                      const float* __restrict__ Wp, const float* __restrict__ bp,
                      float* __restrict__ raw, unsigned int* __restrict__ mEnc, int fd) {
  int e = blockIdx.x * blockDim.x + threadIdx.x;
  if (e >= EE) return;
  if (ev && !ev[e]) return;
  int s = src[e], d = dst[e];
  float r = bp[0];
  for (int j = 0; j < fd; j++) r += x[(size_t)s * fd + j] * Wp[j];
  for (int j = 0; j < fd; j++) r += x[(size_t)d * fd + j] * Wp[fd + j];
  raw[e] = r;
  atomicMax(&mEnc[d], encf(r));
}

__global__ void k_exps(const float* __restrict__ raw, const int* __restrict__ dst,
                       const unsigned char* __restrict__ ev, const unsigned int* __restrict__ mEnc,
                       float* __restrict__ ex, float* __restrict__ ssum) {
  int e = blockIdx.x * blockDim.x + threadIdx.x;
  if (e >= EE) return;
  if (ev && !ev[e]) return;
  int d = dst[e];
  unsigned int me = mEnc[d];
  float m = me ? decf(me) : 0.f;
  float v = expf(raw[e] - m);
  ex[e] = v;
  atomicAdd(&ssum[d], v);
}

// ---------- partition by graph (score computed inline; also zeroes chosen) ----------
// record = { prio = score_bits<<32 | ~e , payload = s<<32 | d }
__global__ void k_part(const int* __restrict__ src, const int* __restrict__ dst,
                       const float* __restrict__ ex, const float* __restrict__ ssum,
                       const unsigned char* __restrict__ ev, float* __restrict__ score,
                       ulonglong2* __restrict__ recs, int* __restrict__ gcnts,
                       unsigned char* __restrict__ chosen) {
  __shared__ int wcnt[TPB / 64][BB];
  __shared__ int bbase[BB];
  int e = blockIdx.x * blockDim.x + threadIdx.x;
  int w = threadIdx.x >> 6, lane = threadIdx.x & 63;
  int valid = 0, s = 0, d = 0, g = 0;
  float sc = 0.f;
  if (e < EE) {
    chosen[e] = 0;
    if (!ev || ev[e]) {
      valid = 1;
      s = src[e];
      d = dst[e];
      g = s / GS;
      float sd = ssum[d];
      sc = ex[e] / (sd > 0.f ? sd : 1.0f) + 0.5f;
      score[e] = sc;
    }
  }
  unsigned long long p = 0;
  if (valid)
    p = (((unsigned long long)__float_as_uint(sc)) << 32) |
        (unsigned int)(~(unsigned int)e);
  int myrank = 0;
#pragma unroll
  for (int gg = 0; gg < BB; gg++) {
    unsigned long long m = __ballot(valid && g == gg);
    if (valid && g == gg) myrank = __popcll(m & ((1ULL << lane) - 1ULL));
    if (lane == 0) wcnt[w][gg] = __popcll(m);
  }
  __syncthreads();
  if (threadIdx.x < BB) {
    int gg = threadIdx.x, tot = 0;
#pragma unroll
    for (int ww = 0; ww < TPB / 64; ww++) {
      int c = wcnt[ww][gg];
      wcnt[ww][gg] = tot;
      tot += c;
    }
    bbase[gg] = tot ? atomicAdd(&gcnts[gg * GPAD], tot) : 0;
  }
  __syncthreads();
  if (valid)
    recs[(size_t)g * CAP + bbase[g] + wcnt[w][g] + myrank] =
        make_ulonglong2(p, (((unsigned long long)(unsigned int)s) << 32) | (unsigned int)d);
}

// ---------- matching: per-graph locally-dominant greedy, all-LDS state ----------
// One block per graph; x4-batched record loads (MLP); full strided best-clear.
__global__ __launch_bounds__(1024) void k_match_g(ulonglong2* __restrict__ recs0,
                                                  ulonglong2* __restrict__ recs1,
                                                  const int* __restrict__ gcnts,
                                                  const unsigned char* __restrict__ nv,
                                                  unsigned char* __restrict__ chosen) {
  __shared__ unsigned long long best[GS];
  __shared__ unsigned int remB[REMW];
  __shared__ int cnt_next;
  const int g = blockIdx.x;
  const int base = g * GS;
  const int t = threadIdx.x, nth = blockDim.x;
  const int lane = t & 63;

  for (int w = t; w < REMW; w += nth) {
    unsigned int bits = 0;
    for (int b = 0; b < 32; b++) {
      int v = w * 32 + b;
      if (v < GS) bits |= (nv ? (nv[base + v] ? 1u : 0u) : 1u) << b;
    }
    remB[w] = bits;
  }
  for (int i = t; i < GS; i += nth) best[i] = 0ULL;
  __syncthreads();

  ulonglong2* bufs[2] = {recs0 + (size_t)g * CAP, recs1 + (size_t)g * CAP};
  int n = gcnts[g * GPAD];
  int cur = 0;

  while (n > 0) {
    // P1: live edges post priority at both endpoints (x4 batched loads)
    for (int i0 = 0; i0 < n; i0 += nth * 4) {
      ulonglong2 r[4];
      int have[4];
#pragma unroll
      for (int k = 0; k < 4; k++) {
        int i = i0 + t + k * nth;
        have[k] = i < n;
        if (have[k]) r[k] = bufs[cur][i];
      }
#pragma unroll
      for (int k = 0; k < 4; k++) {
        if (!have[k]) continue;
        int ls = (int)(r[k].y >> 32) - base, ld = (int)(r[k].y & 0xFFFFFFFFu) - base;
        if (((remB[ls >> 5] >> (ls & 31)) & 1u) && ((remB[ld >> 5] >> (ld & 31)) & 1u)) {
          atomicMax(&best[ls], r[k].x);
          if (ld != ls) atomicMax(&best[ld], r[k].x);
        }
      }
    }
    if (t == 0) cnt_next = 0;
    __syncthreads();
    // P2: local winners commit; survivors compact (x4 batched loads)
    for (int i0 = 0; i0 < n; i0 += nth * 4) {
      ulonglong2 r[4];
      int have[4];
#pragma unroll
      for (int k = 0; k < 4; k++) {
        int i = i0 + t + k * nth;
        have[k] = i < n;
        if (have[k]) r[k] = bufs[cur][i];
      }
#pragma unroll
      for (int k = 0; k < 4; k++) {
        int keep = 0;
        int ls = 0, ld = 0;
        if (have[k]) {
          ls = (int)(r[k].y >> 32) - base;
          ld = (int)(r[k].y & 0xFFFFFFFFu) - base;
          if (((remB[ls >> 5] >> (ls & 31)) & 1u) && ((remB[ld >> 5] >> (ld & 31)) & 1u)) {
            if (best[ls] == r[k].x && best[ld] == r[k].x) {
              int e = (int)(~(unsigned int)(r[k].x & 0xFFFFFFFFu));
              chosen[e] = 1;
              atomicAnd(&remB[ls >> 5], ~(1u << (ls & 31)));
              atomicAnd(&remB[ld >> 5], ~(1u << (ld & 31)));
            } else {
              keep = 1;
            }
          }
        }
        unsigned long long m = __ballot(keep);
        int tot = __popcll(m);
        int pre = __popcll(m & ((1ULL << lane) - 1ULL));
        int b0 = 0;
        if (lane == 0 && tot) b0 = atomicAdd(&cnt_next, tot);
        b0 = __shfl(b0, 0, 64);
        if (keep) bufs[cur ^ 1][b0 + pre] = r[k];
      }
    }
    __syncthreads();
    n = cnt_next;
    // P3: full strided clear (7500 seq LDS writes; no global reads)
    for (int i = t; i < GS; i += nth) best[i] = 0ULL;
    __syncthreads();
    cur ^= 1;
  }
}

// ---------- edge pool: post-matching ----------
__global__ void k_pool_edge(const int* __restrict__ src, const int* __restrict__ dst,
                            const unsigned char* __restrict__ chosen, const float* __restrict__ score,
                            unsigned char* __restrict__ nvout, float* __restrict__ scale,
                            int* __restrict__ partner, int* __restrict__ merged) {
  int e = blockIdx.x * blockDim.x + threadIdx.x;
  if (e >= EE) return;
  if (!chosen[e]) return;
  int s = src[e], d = dst[e];
  scale[s] = score[e];
  if (merged) merged[d] = s;
  if (s != d) {
    nvout[d] = 0;
    partner[s] = d;
  }
}

__global__ void k_newx(const float* __restrict__ x, const int* __restrict__ partner,
                       const float* __restrict__ scale, const unsigned char* __restrict__ nvout,
                       float* __restrict__ newx, int fd) {
  int v = blockIdx.x * blockDim.x + threadIdx.x;
  if (v >= NN) return;
  float sc = scale[v];
  int ok = nvout[v];
  int p = partner[v];
  for (int j = 0; j < fd; j++) {
    float a = x[(size_t)v * fd + j];
    if (p >= 0) a += x[(size_t)p * fd + j];
    newx[(size_t)v * fd + j] = ok ? a * sc : 0.f;
  }
}

// remap with fused cluster-map (reads merged directly)
__global__ void k_remap(const int* __restrict__ src, const int* __restrict__ dst,
                        const int* __restrict__ merged, int* __restrict__ ns, int* __restrict__ nd) {
  int e = blockIdx.x * blockDim.x + threadIdx.x;
  if (e >= EE) return;
  int s = src[e], d = dst[e];
  int ms = merged[s], md = merged[d];
  ns[e] = ms >= 0 ? ms : s;
  nd[e] = md >= 0 ? md : d;
}

// ---------- dedup via hash: keep min original index per (ns,nd) ----------
__device__ __forceinline__ unsigned int ht_hash(unsigned long long key) {
  return (unsigned int)((key * 0x9E3779B97F4A7C15ULL) >> 44) & HT_MASK;
}

__global__ void k_dedup_ins(const int* __restrict__ ns, const int* __restrict__ nd,
                            unsigned long long* __restrict__ htab) {
  int e = blockIdx.x * blockDim.x + threadIdx.x;
  if (e >= EE) return;
  unsigned long long key =
      (unsigned long long)((((unsigned int)ns[e]) << 16) | (unsigned int)nd[e]);
  unsigned long long val = (key << 32) | (unsigned int)e;
  unsigned int h = ht_hash(key);
  for (;;) {
    unsigned long long curv = htab[h];
    if (curv == ~0ULL) {
      unsigned long long prev = atomicCAS(&htab[h], ~0ULL, val);
      if (prev == ~0ULL) break;
      curv = prev;
    }
    if ((curv >> 32) == key) {
      atomicMin(&htab[h], val);
      break;
    }
    h = (h + 1) & HT_MASK;
  }
}

__global__ void k_dedup_mark(const int* __restrict__ ns, const int* __restrict__ nd,
                             const unsigned long long* __restrict__ htab,
                             unsigned char* __restrict__ evout) {
  int e = blockIdx.x * blockDim.x + threadIdx.x;
  if (e >= EE) return;
  unsigned long long key =
      (unsigned long long)((((unsigned int)ns[e]) << 16) | (unsigned int)nd[e]);
  unsigned int h = ht_hash(key);
  for (;;) {
    unsigned long long curv = htab[h];
    if ((curv >> 32) == key) {
      evout[e] = ((curv & 0xFFFFFFFFULL) == (unsigned long long)(unsigned int)e) ? 1 : 0;
      return;
    }
    h = (h + 1) & HT_MASK;
  }
}

// ---------- readout ----------
__global__ void k_graphpool(const float* __restrict__ h, const unsigned char* __restrict__ nv,
                            const int* __restrict__ batch, float* __restrict__ gsum,
                            float* __restrict__ gcnt) {
  int v = blockIdx.x * blockDim.x + threadIdx.x;
  int lane = threadIdx.x & 63;
  int vc = v < NN ? v : NN - 1;
  int b = batch[vc];
  int active = (v < NN) && nv[v];
  float cnt = active ? 1.f : 0.f;
  float val[CC];
  for (int j = 0; j < CC; j++) val[j] = active ? h[(size_t)v * CC + j] : 0.f;
  int b0 = __shfl(b, 0, 64);
  unsigned long long same = __ballot(b == b0);
  if (same == ~0ULL) {
    for (int o = 32; o > 0; o >>= 1) {
      cnt += __shfl_down(cnt, o, 64);
      for (int j = 0; j < CC; j++) val[j] += __shfl_down(val[j], o, 64);
    }
    if (lane == 0 && cnt > 0.f) {
      atomicAdd(&gcnt[b0], cnt);
      for (int j = 0; j < CC; j++) atomicAdd(&gsum[b0 * CC + j], val[j]);
    }
  } else if (active) {
    atomicAdd(&gcnt[b], cnt);
    for (int j = 0; j < CC; j++) atomicAdd(&gsum[b * CC + j], val[j]);
  }
}

__global__ void k_logsm(const float* __restrict__ gsum, const float* __restrict__ gcnt,
                        float* __restrict__ out) {
  int t = threadIdx.x;
  if (t >= BB) return;
  float gr[CC];
  float c = gcnt[t];
  float m = -INFINITY;
  for (int j = 0; j < CC; j++) {
    gr[j] = gsum[t * CC + j] / c;
    m = fmaxf(m, gr[j]);
  }
  float s = 0.f;
  for (int j = 0; j < CC; j++) s += expf(gr[j] - m);
  float l = logf(s);
  for (int j = 0; j < CC; j++) out[t * CC + j] = gr[j] - m - l;
}

// ---------- host ----------
extern "C" void kernel_launch(void* const* d_in, const int* in_sizes, int n_in,
                              void* d_out, int out_size, void* d_ws, size_t ws_size,
                              hipStream_t stream) {
  const float* x = (const float*)d_in[0];
  const int* src = (const int*)d_in[1];
  const int* dst = (const int*)d_in[2];
  const int* batch = (const int*)d_in[3];
  const float* W1 = (const float*)d_in[4];
  const float* b1 = (const float*)d_in[5];
  const float* W2 = (const float*)d_in[6];
  const float* b2 = (const float*)d_in[7];
  const float* Wp1 = (const float*)d_in[8];
  const float* bp1 = (const float*)d_in[9];
  const float* Wp2 = (const float*)d_in[10];
  const float* bp2 = (const float*)d_in[11];
  float* out = (float*)d_out;

  char* wsb = (char*)d_ws;
  size_t off = 0;
  auto A = [&](size_t bytes) -> char* {
    char* r = wsb + off;
    off = (off + bytes + 255) & ~(size_t)255;
    return r;
  };
  float* h1pre = (float*)A((size_t)NN * HH * 4);
  float* h1out = (float*)A((size_t)NN * HH * 4);
  float* deg = (float*)A((size_t)NN * 4);
  float* dinv = (float*)A((size_t)NN * 4);
  unsigned char* hasloop = (unsigned char*)A(NN);
  unsigned char* addloop = (unsigned char*)A(NN);
  float* raw = (float*)A((size_t)EE * 4);
  float* ex = (float*)A((size_t)EE * 4);
  float* score = (float*)A((size_t)EE * 4);
  unsigned int* mEnc = (unsigned int*)A((size_t)NN * 4);
  float* ssum = (float*)A((size_t)NN * 4);
  unsigned char* chosen = (unsigned char*)A(EE);
  unsigned char* nv1 = (unsigned char*)A(NN);
  unsigned char* nv2 = (unsigned char*)A(NN);
  float* scale = (float*)A((size_t)NN * 4);
  int* partner = (int*)A((size_t)NN * 4);
  float* newx1 = (float*)A((size_t)NN * HH * 4);
  int* merged = (int*)A((size_t)NN * 4);
  int* ns = (int*)A((size_t)EE * 4);
  int* nd = (int*)A((size_t)EE * 4);
  unsigned char* ev1 = (unsigned char*)A(EE);
  unsigned long long* htab = (unsigned long long*)A((size_t)HT_SIZE * 8);
  float* h2pre = (float*)A((size_t)NN * CC * 4);
  float* h2out = (float*)A((size_t)NN * CC * 4);
  float* newx2 = (float*)A((size_t)NN * CC * 4);
  ulonglong2* recs0 = (ulonglong2*)A((size_t)BB * CAP * 16);
  ulonglong2* recs1 = (ulonglong2*)A((size_t)BB * CAP * 16);
  int* gcnts = (int*)A((size_t)BB * GPAD * 4);
  float* gsum = (float*)A((size_t)BB * CC * 4);
  float* gcnt = (float*)A((size_t)BB * 4);
  (void)ws_size; (void)n_in; (void)in_sizes; (void)out_size;

  const int GE = ngrid(EE), GN = ngrid(NN);

  // ===== stage 1: GCNConv(384->6) + ReLU =====
  hipLaunchKernelGGL(k_mm1, dim3((NN + 3) / 4), dim3(TPB), 0, stream, x, W1, h1pre);
  hipLaunchKernelGGL(k_prep, dim3(GN), dim3(TPB), 0, stream, deg, hasloop, mEnc, ssum, h1out, HH, gcnts, gsum, gcnt,
                     (const unsigned char*)nullptr, nv1, scale, merged, partner);
  hipLaunchKernelGGL(k_deg, dim3(GE), dim3(TPB), 0, stream, src, dst, (const unsigned char*)nullptr, deg, hasloop);
  hipLaunchKernelGGL(k_dinv, dim3(GN), dim3(TPB), 0, stream, deg, hasloop, (const unsigned char*)nullptr, dinv, addloop);
  hipLaunchKernelGGL(k_gcn_agg, dim3(GE), dim3(TPB), 0, stream, src, dst, (const unsigned char*)nullptr, dinv, h1pre, h1out, HH);
  hipLaunchKernelGGL(k_gcn_fin, dim3(GN), dim3(TPB), 0, stream, h1pre, dinv, addloop, b1, h1out, HH, 1);

  // ===== edge pool 1 =====
  hipLaunchKernelGGL(k_raw, dim3(GE), dim3(TPB), 0, stream, h1out, src, dst, (const unsigned char*)nullptr, Wp1, bp1, raw, mEnc, HH);
  hipLaunchKernelGGL(k_exps, dim3(GE), dim3(TPB), 0, stream, raw, dst, (const unsigned char*)nullptr, mEnc, ex, ssum);
  hipLaunchKernelGGL(k_part, dim3(GE), dim3(TPB), 0, stream, src, dst, ex, ssum, (const unsigned char*)nullptr, score, recs0, gcnts, chosen);
  hipLaunchKernelGGL(k_match_g, dim3(BB), dim3(1024), 0, stream, recs0, recs1, gcnts, (const unsigned char*)nullptr, chosen);
  hipLaunchKernelGGL(k_pool_edge, dim3(GE), dim3(TPB), 0, stream, src, dst, chosen, score, nv1, scale, partner, merged);
  hipLaunchKernelGGL(k_newx, dim3(GN), dim3(TPB), 0, stream, h1out, partner, scale, nv1, newx1, HH);
  hipLaunchKernelGGL(k_remap, dim3(GE), dim3(TPB), 0, stream, src, dst, merged, ns, nd);
  hipMemsetAsync(htab, 0xFF, (size_t)HT_SIZE * 8, stream);
  hipLaunchKernelGGL(k_dedup_ins, dim3(GE), dim3(TPB), 0, stream, ns, nd, htab);
  hipLaunchKernelGGL(k_dedup_mark, dim3(GE), dim3(TPB), 0, stream, ns, nd, htab, ev1);

  // ===== stage 2: GCNConv(6->10) =====
  hipLaunchKernelGGL(k_mm2, dim3(GN), dim3(TPB), 0, stream, newx1, W2, h2pre);
  hipLaunchKernelGGL(k_prep, dim3(GN), dim3(TPB), 0, stream, deg, hasloop, mEnc, ssum, h2out, CC, gcnts, gsum, gcnt,
                     (const unsigned char*)nv1, nv2, scale, (int*)nullptr, partner);
  hipLaunchKernelGGL(k_deg, dim3(GE), dim3(TPB), 0, stream, ns, nd, (const unsigned char*)ev1, deg, hasloop);
  hipLaunchKernelGGL(k_dinv, dim3(GN), dim3(TPB), 0, stream, deg, hasloop, (const unsigned char*)nv1, dinv, addloop);
  hipLaunchKernelGGL(k_gcn_agg, dim3(GE), dim3(TPB), 0, stream, ns, nd, (const unsigned char*)ev1, dinv, h2pre, h2out, CC);
  hipLaunchKernelGGL(k_gcn_fin, dim3(GN), dim3(TPB), 0, stream, h2pre, dinv, addloop, b2, h2out, CC, 0);

  // ===== edge pool 2 =====
  hipLaunchKernelGGL(k_raw, dim3(GE), dim3(TPB), 0, stream, h2out, ns, nd, (const unsigned char*)ev1, Wp2, bp2, raw, mEnc, CC);
  hipLaunchKernelGGL(k_exps, dim3(GE), dim3(TPB), 0, stream, raw, nd, (const unsigned char*)ev1, mEnc, ex, ssum);
  hipLaunchKernelGGL(k_part, dim3(GE), dim3(TPB), 0, stream, ns, nd, ex, ssum, (const unsigned char*)ev1, score, recs0, gcnts, chosen);
  hipLaunchKernelGGL(k_match_g, dim3(BB), dim3(1024), 0, stream, recs0, recs1, gcnts, (const unsigned char*)nv1, chosen);
  hipLaunchKernelGGL(k_pool_edge, dim3(GE), dim3(TPB), 0, stream, ns, nd, chosen, score, nv2, scale, partner, (int*)nullptr);
  hipLaunchKernelGGL(k_newx, dim3(GN), dim3(TPB), 0, stream, h2out, partner, scale, nv2, newx2, CC);

  // ===== readout =====
  hipLaunchKernelGGL(k_graphpool, dim3(GN), dim3(TPB), 0, stream, newx2, nv2, batch, gsum, gcnt);
  hipLaunchKernelGGL(k_logsm, dim3(1), dim3(64), 0, stream, gsum, gcnt, out);
}

// Round 8
// 1987.263 us; speedup vs baseline: 2.7343x; 1.0154x over previous
//
#include <hip/hip_runtime.h>
#include <math.h>

#define NN 60000
#define BB 8
#define GS 7500   // nodes per graph
#define FF 384
#define EE 600000
#define HH 6
#define CC 10
#define HT_BITS 20
#define HT_SIZE (1u << HT_BITS)
#define HT_MASK (HT_SIZE - 1u)
#define TPB 256
#define CAP 80000  // per-graph edge capacity
#define REMW ((GS + 31) / 32)
#define GPAD 32    // gcnts padding: one counter per 128B (R3 lesson)

static inline int ngrid(int n) { return (n + TPB - 1) / TPB; }

// ---------- helpers ----------
__device__ __forceinline__ unsigned int encf(float v) {
  unsigned int b = __float_as_uint(v);
  return (b & 0x80000000u) ? ~b : (b | 0x80000000u);
}
__device__ __forceinline__ float decf(unsigned int u) {
  unsigned int b = (u & 0x80000000u) ? (u & 0x7FFFFFFFu) : ~u;
  return __uint_as_float(b);
}
__device__ __forceinline__ unsigned long long mkprio(float sc, int e) {
  return (((unsigned long long)__float_as_uint(sc)) << 32) |
         (unsigned int)(~(unsigned int)e);
}

// ---------- stage 1 matmul: h1pre = x @ W1 ----------
__global__ void k_mm1(const float* __restrict__ x, const float* __restrict__ W,
                      float* __restrict__ out) {
  __shared__ float Ws[FF * HH];
  for (int i = threadIdx.x; i < FF * HH; i += blockDim.x) Ws[i] = W[i];
  __syncthreads();
  int wave = threadIdx.x >> 6, lane = threadIdx.x & 63;
  int node = blockIdx.x * 4 + wave;
  if (node >= NN) return;
  const float* xr = x + (size_t)node * FF;
  float acc[HH] = {0.f, 0.f, 0.f, 0.f, 0.f, 0.f};
  for (int k = lane; k < FF; k += 64) {
    float xv = xr[k];
#pragma unroll
    for (int j = 0; j < HH; j++) acc[j] += xv * Ws[k * HH + j];
  }
#pragma unroll
  for (int j = 0; j < HH; j++) {
#pragma unroll
    for (int o = 32; o > 0; o >>= 1) acc[j] += __shfl_down(acc[j], o, 64);
  }
  if (lane == 0) {
#pragma unroll
    for (int j = 0; j < HH; j++) out[(size_t)node * HH + j] = acc[j];
  }
}

// ---------- fused per-stage init ----------
__global__ void k_prep(float* __restrict__ deg, unsigned char* __restrict__ hasloop,
                       unsigned int* __restrict__ mEnc, float* __restrict__ ssum,
                       float* __restrict__ hout, int fd, int* __restrict__ gcnts,
                       float* __restrict__ gsum, float* __restrict__ gcnt,
                       const unsigned char* __restrict__ nvin, unsigned char* __restrict__ nvout,
                       float* __restrict__ scale, int* __restrict__ merged,
                       int* __restrict__ partner, unsigned long long* __restrict__ best64,
                       unsigned char* __restrict__ remG) {
  int v = blockIdx.x * blockDim.x + threadIdx.x;
  if (v >= NN) return;
  deg[v] = 0.f;
  hasloop[v] = 0;
  mEnc[v] = 0;
  ssum[v] = 0.f;
  for (int j = 0; j < fd; j++) hout[(size_t)v * fd + j] = 0.f;
  unsigned char nvv = nvin ? nvin[v] : 1;
  nvout[v] = nvv;
  remG[v] = nvv;
  best64[v] = 0ULL;
  scale[v] = 1.0f;
  if (merged) merged[v] = -1;
  partner[v] = -1;
  if (v < BB * GPAD) gcnts[v] = 0;
  if (v < BB * CC) gsum[v] = 0.f;
  if (v < BB) gcnt[v] = 0.f;
}

// ---------- generic GCN conv pieces ----------
__global__ void k_deg(const int* __restrict__ src, const int* __restrict__ dst,
                      const unsigned char* __restrict__ ev, float* __restrict__ deg,
                      unsigned char* __restrict__ hasloop) {
  int e = blockIdx.x * blockDim.x + threadIdx.x;
  if (e >= EE) return;
  if (ev && !ev[e]) return;
  int d = dst[e];
  atomicAdd(&deg[d], 1.0f);
  if (src[e] == d) hasloop[d] = 1;
}

__global__ void k_dinv(const float* __restrict__ deg, const unsigned char* __restrict__ hasloop,
                       const unsigned char* __restrict__ nv, float* __restrict__ dinv,
                       unsigned char* __restrict__ addloop) {
  int v = blockIdx.x * blockDim.x + threadIdx.x;
  if (v >= NN) return;
  int nvv = nv ? (int)nv[v] : 1;
  unsigned char al = (nvv && !hasloop[v]) ? 1 : 0;
  float d = deg[v] + (float)al;
  dinv[v] = d > 0.f ? 1.0f / sqrtf(fmaxf(d, 1e-12f)) : 0.f;
  addloop[v] = al;
}

__global__ void k_gcn_agg(const int* __restrict__ src, const int* __restrict__ dst,
                          const unsigned char* __restrict__ ev, const float* __restrict__ dinv,
                          const float* __restrict__ h, float* __restrict__ out, int fd) {
  int e = blockIdx.x * blockDim.x + threadIdx.x;
  if (e >= EE) return;
  if (ev && !ev[e]) return;
  int s = src[e], d = dst[e];
  float c = dinv[s] * dinv[d];
  for (int j = 0; j < fd; j++)
    atomicAdd(&out[(size_t)d * fd + j], h[(size_t)s * fd + j] * c);
}

__global__ void k_gcn_fin(const float* __restrict__ h, const float* __restrict__ dinv,
                          const unsigned char* __restrict__ addloop, const float* __restrict__ b,
                          float* __restrict__ out, int fd, int relu) {
  int v = blockIdx.x * blockDim.x + threadIdx.x;
  if (v >= NN) return;
  float c = addloop[v] ? dinv[v] * dinv[v] : 0.f;
  for (int j = 0; j < fd; j++) {
    float o = out[(size_t)v * fd + j] + c * h[(size_t)v * fd + j] + b[j];
    if (relu) o = fmaxf(o, 0.f);
    out[(size_t)v * fd + j] = o;
  }
}

// ---------- edge pool: scores ----------
__global__ void k_raw(const float* __restrict__ x, const int* __restrict__ src,
                      const int* __restrict__ dst, const unsigned char* __restrict__ ev,
                      const float* __restrict__ Wp, const float* __restrict__ bp,
                      float* __restrict__ raw, unsigned int* __restrict__ mEnc, int fd) {
  int e = blockIdx.x * blockDim.x + threadIdx.x;
  if (e >= EE) return;
  if (ev && !ev[e]) return;
  int s = src[e], d = dst[e];
  float r = bp[0];
  for (int j = 0; j < fd; j++) r += x[(size_t)s * fd + j] * Wp[j];
  for (int j = 0; j < fd; j++) r += x[(size_t)d * fd + j] * Wp[fd + j];
  raw[e] = r;
  atomicMax(&mEnc[d], encf(r));
}

__global__ void k_exps(const float* __restrict__ raw, const int* __restrict__ dst,
                       const unsigned char* __restrict__ ev, const unsigned int* __restrict__ mEnc,
                       float* __restrict__ ex, float* __restrict__ ssum) {
  int e = blockIdx.x * blockDim.x + threadIdx.x;
  if (e >= EE) return;
  if (ev && !ev[e]) return;
  int d = dst[e];
  unsigned int me = mEnc[d];
  float m = me ? decf(me) : 0.f;
  float v = expf(raw[e] - m);
  ex[e] = v;
  atomicAdd(&ssum[d], v);
}

// ---------- matching round 1, phase A (full GPU): score + post best64 ----------
__global__ void k_r1post(const int* __restrict__ src, const int* __restrict__ dst,
                         const float* __restrict__ ex, const float* __restrict__ ssum,
                         const unsigned char* __restrict__ ev, const unsigned char* __restrict__ remG,
                         float* __restrict__ score, unsigned long long* __restrict__ best64,
                         unsigned char* __restrict__ chosen) {
  int e = blockIdx.x * blockDim.x + threadIdx.x;
  if (e >= EE) return;
  chosen[e] = 0;
  if (ev && !ev[e]) return;
  int s = src[e], d = dst[e];
  if (!remG[s] || !remG[d]) return;
  float sd = ssum[d];
  float sc = ex[e] / (sd > 0.f ? sd : 1.0f) + 0.5f;
  score[e] = sc;
  unsigned long long p = mkprio(sc, e);
  atomicMax(&best64[s], p);
  if (d != s) atomicMax(&best64[d], p);
}

// ---------- matching round 1, phase B (full GPU): select winners + compact survivors ----------
__global__ void k_r1sel(const int* __restrict__ src, const int* __restrict__ dst,
                        const float* __restrict__ score, const unsigned char* __restrict__ ev,
                        unsigned char* __restrict__ remG,
                        const unsigned long long* __restrict__ best64,
                        unsigned char* __restrict__ chosen, ulonglong2* __restrict__ recs,
                        int* __restrict__ gcnts) {
  __shared__ int wcnt[TPB / 64][BB];
  __shared__ int bbase[BB];
  int e = blockIdx.x * blockDim.x + threadIdx.x;
  int w = threadIdx.x >> 6, lane = threadIdx.x & 63;
  int keep = 0, s = 0, d = 0, g = 0;
  unsigned long long p = 0;
  if (e < EE && (!ev || ev[e])) {
    s = src[e];
    d = dst[e];
    g = s / GS;
    // benign race (same as LDS P2): winners only write remG; stale-1 losers
    // become survivors (filtered next round), 0-reads are truly dead.
    if (remG[s] && remG[d]) {
      p = mkprio(score[e], e);
      if (best64[s] == p && best64[d] == p) {
        chosen[e] = 1;
        remG[s] = 0;
        remG[d] = 0;
      } else {
        keep = 1;
      }
    }
  }
  int myrank = 0;
#pragma unroll
  for (int gg = 0; gg < BB; gg++) {
    unsigned long long m = __ballot(keep && g == gg);
    if (keep && g == gg) myrank = __popcll(m & ((1ULL << lane) - 1ULL));
    if (lane == 0) wcnt[w][gg] = __popcll(m);
  }
  __syncthreads();
  if (threadIdx.x < BB) {
    int gg = threadIdx.x, tot = 0;
#pragma unroll
    for (int ww = 0; ww < TPB / 64; ww++) {
      int c = wcnt[ww][gg];
      wcnt[ww][gg] = tot;
      tot += c;
    }
    bbase[gg] = tot ? atomicAdd(&gcnts[gg * GPAD], tot) : 0;
  }
  __syncthreads();
  if (keep)
    recs[(size_t)g * CAP + bbase[g] + wcnt[w][g] + myrank] =
        make_ulonglong2(p, (((unsigned long long)(unsigned int)s) << 32) | (unsigned int)d);
}

// ---------- matching rounds 2+: per-graph LDS fixpoint (R7 structure) ----------
__global__ __launch_bounds__(1024) void k_match_g(ulonglong2* __restrict__ recs0,
                                                  ulonglong2* __restrict__ recs1,
                                                  const int* __restrict__ gcnts,
                                                  const unsigned char* __restrict__ remG,
                                                  unsigned char* __restrict__ chosen) {
  __shared__ unsigned long long best[GS];
  __shared__ unsigned int remB[REMW];
  __shared__ int cnt_next;
  const int g = blockIdx.x;
  const int base = g * GS;
  const int t = threadIdx.x, nth = blockDim.x;
  const int lane = t & 63;

  for (int w = t; w < REMW; w += nth) {
    unsigned int bits = 0;
    for (int b = 0; b < 32; b++) {
      int v = w * 32 + b;
      if (v < GS) bits |= (remG[base + v] ? 1u : 0u) << b;
    }
    remB[w] = bits;
  }
  for (int i = t; i < GS; i += nth) best[i] = 0ULL;
  __syncthreads();

  ulonglong2* bufs[2] = {recs0 + (size_t)g * CAP, recs1 + (size_t)g * CAP};
  int n = gcnts[g * GPAD];
  int cur = 0;

  while (n > 0) {
    // P1: live edges post priority (x4 batched loads for MLP)
    for (int i0 = 0; i0 < n; i0 += nth * 4) {
      ulonglong2 r[4];
      int have[4];
#pragma unroll
      for (int k = 0; k < 4; k++) {
        int i = i0 + t + k * nth;
        have[k] = i < n;
        if (have[k]) r[k] = bufs[cur][i];
      }
#pragma unroll
      for (int k = 0; k < 4; k++) {
        if (!have[k]) continue;
        int ls = (int)(r[k].y >> 32) - base, ld = (int)(r[k].y & 0xFFFFFFFFu) - base;
        if (((remB[ls >> 5] >> (ls & 31)) & 1u) && ((remB[ld >> 5] >> (ld & 31)) & 1u)) {
          atomicMax(&best[ls], r[k].x);
          if (ld != ls) atomicMax(&best[ld], r[k].x);
        }
      }
    }
    if (t == 0) cnt_next = 0;
    __syncthreads();
    // P2: winners commit; survivors compact
    for (int i0 = 0; i0 < n; i0 += nth * 4) {
      ulonglong2 r[4];
      int have[4];
#pragma unroll
      for (int k = 0; k < 4; k++) {
        int i = i0 + t + k * nth;
        have[k] = i < n;
        if (have[k]) r[k] = bufs[cur][i];
      }
#pragma unroll
      for (int k = 0; k < 4; k++) {
        int keep = 0;
        int ls = 0, ld = 0;
        if (have[k]) {
          ls = (int)(r[k].y >> 32) - base;
          ld = (int)(r[k].y & 0xFFFFFFFFu) - base;
          if (((remB[ls >> 5] >> (ls & 31)) & 1u) && ((remB[ld >> 5] >> (ld & 31)) & 1u)) {
            if (best[ls] == r[k].x && best[ld] == r[k].x) {
              int e = (int)(~(unsigned int)(r[k].x & 0xFFFFFFFFu));
              chosen[e] = 1;
              atomicAnd(&remB[ls >> 5], ~(1u << (ls & 31)));
              atomicAnd(&remB[ld >> 5], ~(1u << (ld & 31)));
            } else {
              keep = 1;
            }
          }
        }
        unsigned long long m = __ballot(keep);
        int tot = __popcll(m);
        int pre = __popcll(m & ((1ULL << lane) - 1ULL));
        int b0 = 0;
        if (lane == 0 && tot) b0 = atomicAdd(&cnt_next, tot);
        b0 = __shfl(b0, 0, 64);
        if (keep) bufs[cur ^ 1][b0 + pre] = r[k];
      }
    }
    __syncthreads();
    n = cnt_next;
    // P3: full strided clear
    for (int i = t; i < GS; i += nth) best[i] = 0ULL;
    __syncthreads();
    cur ^= 1;
  }
}

// ---------- edge pool: post-matching ----------
__global__ void k_pool_edge(const int* __restrict__ src, const int* __restrict__ dst,
                            const unsigned char* __restrict__ chosen, const float* __restrict__ score,
                            unsigned char* __restrict__ nvout, float* __restrict__ scale,
                            int* __restrict__ partner, int* __restrict__ merged) {
  int e = blockIdx.x * blockDim.x + threadIdx.x;
  if (e >= EE) return;
  if (!chosen[e]) return;
  int s = src[e], d = dst[e];
  scale[s] = score[e];
  if (merged) merged[d] = s;
  if (s != d) {
    nvout[d] = 0;
    partner[s] = d;
  }
}

// fused: newx1 (never materialized) -> h2pre = newx1 @ W2
__global__ void k_newx_mm2(const float* __restrict__ h1, const int* __restrict__ partner,
                           const float* __restrict__ scale, const unsigned char* __restrict__ nvout,
                           const float* __restrict__ W2, float* __restrict__ h2pre) {
  int v = blockIdx.x * blockDim.x + threadIdx.x;
  if (v >= NN) return;
  float sc = scale[v];
  int ok = nvout[v];
  int p = partner[v];
  float nx[HH];
#pragma unroll
  for (int j = 0; j < HH; j++) {
    float a = h1[(size_t)v * HH + j];
    if (p >= 0) a += h1[(size_t)p * HH + j];
    nx[j] = ok ? a * sc : 0.f;
  }
#pragma unroll
  for (int c = 0; c < CC; c++) {
    float a = 0.f;
#pragma unroll
    for (int j = 0; j < HH; j++) a += nx[j] * W2[j * CC + c];
    h2pre[(size_t)v * CC + c] = a;
  }
}

// fused remap + dedup insert
__device__ __forceinline__ unsigned int ht_hash(unsigned long long key) {
  return (unsigned int)((key * 0x9E3779B97F4A7C15ULL) >> 44) & HT_MASK;
}

__global__ void k_remap_ins(const int* __restrict__ src, const int* __restrict__ dst,
                            const int* __restrict__ merged, int* __restrict__ ns,
                            int* __restrict__ nd, unsigned long long* __restrict__ htab) {
  int e = blockIdx.x * blockDim.x + threadIdx.x;
  if (e >= EE) return;
  int s = src[e], d = dst[e];
  int ms = merged[s], md = merged[d];
  int a = ms >= 0 ? ms : s;
  int b = md >= 0 ? md : d;
  ns[e] = a;
  nd[e] = b;
  unsigned long long key =
      (unsigned long long)((((unsigned int)a) << 16) | (unsigned int)b);
  unsigned long long val = (key << 32) | (unsigned int)e;
  unsigned int h = ht_hash(key);
  for (;;) {
    unsigned long long curv = htab[h];
    if (curv == ~0ULL) {
      unsigned long long prev = atomicCAS(&htab[h], ~0ULL, val);
      if (prev == ~0ULL) break;
      curv = prev;
    }
    if ((curv >> 32) == key) {
      atomicMin(&htab[h], val);
      break;
    }
    h = (h + 1) & HT_MASK;
  }
}

__global__ void k_dedup_mark(const int* __restrict__ ns, const int* __restrict__ nd,
                             const unsigned long long* __restrict__ htab,
                             unsigned char* __restrict__ evout) {
  int e = blockIdx.x * blockDim.x + threadIdx.x;
  if (e >= EE) return;
  unsigned long long key =
      (unsigned long long)((((unsigned int)ns[e]) << 16) | (unsigned int)nd[e]);
  unsigned int h = ht_hash(key);
  for (;;) {
    unsigned long long curv = htab[h];
    if ((curv >> 32) == key) {
      evout[e] = ((curv & 0xFFFFFFFFULL) == (unsigned long long)(unsigned int)e) ? 1 : 0;
      return;
    }
    h = (h + 1) & HT_MASK;
  }
}

// fused: newx2 (never materialized) -> graph mean-pool accumulate
__global__ void k_newx_pool(const float* __restrict__ h2, const int* __restrict__ partner,
                            const float* __restrict__ scale, const unsigned char* __restrict__ nv,
                            float* __restrict__ gsum, float* __restrict__ gcnt) {
  int v = blockIdx.x * blockDim.x + threadIdx.x;
  int lane = threadIdx.x & 63;
  int b = (v < NN ? v : NN - 1) / GS;
  int active = (v < NN) && nv[v];
  float cnt = active ? 1.f : 0.f;
  float val[CC];
  if (active) {
    float sc = scale[v];
    int p = partner[v];
    for (int j = 0; j < CC; j++) {
      float a = h2[(size_t)v * CC + j];
      if (p >= 0) a += h2[(size_t)p * CC + j];
      val[j] = a * sc;
    }
  } else {
    for (int j = 0; j < CC; j++) val[j] = 0.f;
  }
  int b0 = __shfl(b, 0, 64);
  unsigned long long same = __ballot(b == b0);
  if (same == ~0ULL) {
    for (int o = 32; o > 0; o >>= 1) {
      cnt += __shfl_down(cnt, o, 64);
      for (int j = 0; j < CC; j++) val[j] += __shfl_down(val[j], o, 64);
    }
    if (lane == 0 && cnt > 0.f) {
      atomicAdd(&gcnt[b0], cnt);
      for (int j = 0; j < CC; j++) atomicAdd(&gsum[b0 * CC + j], val[j]);
    }
  } else if (active) {
    atomicAdd(&gcnt[b], cnt);
    for (int j = 0; j < CC; j++) atomicAdd(&gsum[b * CC + j], val[j]);
  }
}

__global__ void k_logsm(const float* __restrict__ gsum, const float* __restrict__ gcnt,
                        float* __restrict__ out) {
  int t = threadIdx.x;
  if (t >= BB) return;
  float gr[CC];
  float c = gcnt[t];
  float m = -INFINITY;
  for (int j = 0; j < CC; j++) {
    gr[j] = gsum[t * CC + j] / c;
    m = fmaxf(m, gr[j]);
  }
  float s = 0.f;
  for (int j = 0; j < CC; j++) s += expf(gr[j] - m);
  float l = logf(s);
  for (int j = 0; j < CC; j++) out[t * CC + j] = gr[j] - m - l;
}

// ---------- host ----------
extern "C" void kernel_launch(void* const* d_in, const int* in_sizes, int n_in,
                              void* d_out, int out_size, void* d_ws, size_t ws_size,
                              hipStream_t stream) {
  const float* x = (const float*)d_in[0];
  const int* src = (const int*)d_in[1];
  const int* dst = (const int*)d_in[2];
  const float* W1 = (const float*)d_in[4];
  const float* b1 = (const float*)d_in[5];
  const float* W2 = (const float*)d_in[6];
  const float* b2 = (const float*)d_in[7];
  const float* Wp1 = (const float*)d_in[8];
  const float* bp1 = (const float*)d_in[9];
  const float* Wp2 = (const float*)d_in[10];
  const float* bp2 = (const float*)d_in[11];
  float* out = (float*)d_out;

  char* wsb = (char*)d_ws;
  size_t off = 0;
  auto A = [&](size_t bytes) -> char* {
    char* r = wsb + off;
    off = (off + bytes + 255) & ~(size_t)255;
    return r;
  };
  float* h1pre = (float*)A((size_t)NN * HH * 4);
  float* h1out = (float*)A((size_t)NN * HH * 4);
  float* deg = (float*)A((size_t)NN * 4);
  float* dinv = (float*)A((size_t)NN * 4);
  unsigned char* hasloop = (unsigned char*)A(NN);
  unsigned char* addloop = (unsigned char*)A(NN);
  float* raw = (float*)A((size_t)EE * 4);
  float* ex = (float*)A((size_t)EE * 4);
  float* score = (float*)A((size_t)EE * 4);
  unsigned int* mEnc = (unsigned int*)A((size_t)NN * 4);
  float* ssum = (float*)A((size_t)NN * 4);
  unsigned char* chosen = (unsigned char*)A(EE);
  unsigned char* nv1 = (unsigned char*)A(NN);
  unsigned char* nv2 = (unsigned char*)A(NN);
  float* scale = (float*)A((size_t)NN * 4);
  int* partner = (int*)A((size_t)NN * 4);
  int* merged = (int*)A((size_t)NN * 4);
  int* ns = (int*)A((size_t)EE * 4);
  int* nd = (int*)A((size_t)EE * 4);
  unsigned char* ev1 = (unsigned char*)A(EE);
  unsigned long long* htab = (unsigned long long*)A((size_t)HT_SIZE * 8);
  float* h2pre = (float*)A((size_t)NN * CC * 4);
  float* h2out = (float*)A((size_t)NN * CC * 4);
  unsigned long long* best64 = (unsigned long long*)A((size_t)NN * 8);
  unsigned char* remG = (unsigned char*)A(NN);
  ulonglong2* recs0 = (ulonglong2*)A((size_t)BB * CAP * 16);
  ulonglong2* recs1 = (ulonglong2*)A((size_t)BB * CAP * 16);
  int* gcnts = (int*)A((size_t)BB * GPAD * 4);
  float* gsum = (float*)A((size_t)BB * CC * 4);
  float* gcnt = (float*)A((size_t)BB * 4);
  (void)ws_size; (void)n_in; (void)in_sizes; (void)out_size;

  const int GE = ngrid(EE), GN = ngrid(NN);

  // ===== stage 1: GCNConv(384->6) + ReLU =====
  hipMemsetAsync(htab, 0xFF, (size_t)HT_SIZE * 8, stream);
  hipLaunchKernelGGL(k_mm1, dim3((NN + 3) / 4), dim3(TPB), 0, stream, x, W1, h1pre);
  hipLaunchKernelGGL(k_prep, dim3(GN), dim3(TPB), 0, stream, deg, hasloop, mEnc, ssum, h1out, HH, gcnts, gsum, gcnt,
                     (const unsigned char*)nullptr, nv1, scale, merged, partner, best64, remG);
  hipLaunchKernelGGL(k_deg, dim3(GE), dim3(TPB), 0, stream, src, dst, (const unsigned char*)nullptr, deg, hasloop);
  hipLaunchKernelGGL(k_dinv, dim3(GN), dim3(TPB), 0, stream, deg, hasloop, (const unsigned char*)nullptr, dinv, addloop);
  hipLaunchKernelGGL(k_gcn_agg, dim3(GE), dim3(TPB), 0, stream, src, dst, (const unsigned char*)nullptr, dinv, h1pre, h1out, HH);
  hipLaunchKernelGGL(k_gcn_fin, dim3(GN), dim3(TPB), 0, stream, h1pre, dinv, addloop, b1, h1out, HH, 1);

  // ===== edge pool 1 =====
  hipLaunchKernelGGL(k_raw, dim3(GE), dim3(TPB), 0, stream, h1out, src, dst, (const unsigned char*)nullptr, Wp1, bp1, raw, mEnc, HH);
  hipLaunchKernelGGL(k_exps, dim3(GE), dim3(TPB), 0, stream, raw, dst, (const unsigned char*)nullptr, mEnc, ex, ssum);
  hipLaunchKernelGGL(k_r1post, dim3(GE), dim3(TPB), 0, stream, src, dst, ex, ssum, (const unsigned char*)nullptr, remG, score, best64, chosen);
  hipLaunchKernelGGL(k_r1sel, dim3(GE), dim3(TPB), 0, stream, src, dst, score, (const unsigned char*)nullptr, remG, best64, chosen, recs0, gcnts);
  hipLaunchKernelGGL(k_match_g, dim3(BB), dim3(1024), 0, stream, recs0, recs1, gcnts, remG, chosen);
  hipLaunchKernelGGL(k_pool_edge, dim3(GE), dim3(TPB), 0, stream, src, dst, chosen, score, nv1, scale, partner, merged);
  hipLaunchKernelGGL(k_newx_mm2, dim3(GN), dim3(TPB), 0, stream, h1out, partner, scale, nv1, W2, h2pre);
  hipLaunchKernelGGL(k_remap_ins, dim3(GE), dim3(TPB), 0, stream, src, dst, merged, ns, nd, htab);
  hipLaunchKernelGGL(k_dedup_mark, dim3(GE), dim3(TPB), 0, stream, ns, nd, htab, ev1);

  // ===== stage 2: GCNConv(6->10) =====
  hipLaunchKernelGGL(k_prep, dim3(GN), dim3(TPB), 0, stream, deg, hasloop, mEnc, ssum, h2out, CC, gcnts, gsum, gcnt,
                     (const unsigned char*)nv1, nv2, scale, (int*)nullptr, partner, best64, remG);
  hipLaunchKernelGGL(k_deg, dim3(GE), dim3(TPB), 0, stream, ns, nd, (const unsigned char*)ev1, deg, hasloop);
  hipLaunchKernelGGL(k_dinv, dim3(GN), dim3(TPB), 0, stream, deg, hasloop, (const unsigned char*)nv1, dinv, addloop);
  hipLaunchKernelGGL(k_gcn_agg, dim3(GE), dim3(TPB), 0, stream, ns, nd, (const unsigned char*)ev1, dinv, h2pre, h2out, CC);
  hipLaunchKernelGGL(k_gcn_fin, dim3(GN), dim3(TPB), 0, stream, h2pre, dinv, addloop, b2, h2out, CC, 0);

  // ===== edge pool 2 =====
  hipLaunchKernelGGL(k_raw, dim3(GE), dim3(TPB), 0, stream, h2out, ns, nd, (const unsigned char*)ev1, Wp2, bp2, raw, mEnc, CC);
  hipLaunchKernelGGL(k_exps, dim3(GE), dim3(TPB), 0, stream, raw, nd, (const unsigned char*)ev1, mEnc, ex, ssum);
  hipLaunchKernelGGL(k_r1post, dim3(GE), dim3(TPB), 0, stream, ns, nd, ex, ssum, (const unsigned char*)ev1, remG, score, best64, chosen);
  hipLaunchKernelGGL(k_r1sel, dim3(GE), dim3(TPB), 0, stream, ns, nd, score, (const unsigned char*)ev1, remG, best64, chosen, recs0, gcnts);
  hipLaunchKernelGGL(k_match_g, dim3(BB), dim3(1024), 0, stream, recs0, recs1, gcnts, remG, chosen);
  hipLaunchKernelGGL(k_pool_edge, dim3(GE), dim3(TPB), 0, stream, ns, nd, chosen, score, nv2, scale, partner, (int*)nullptr);

  // ===== readout =====
  hipLaunchKernelGGL(k_newx_pool, dim3(GN), dim3(TPB), 0, stream, h2out, partner, scale, nv2, gsum, gcnt);
  hipLaunchKernelGGL(k_logsm, dim3(1), dim3(64), 0, stream, gsum, gcnt, out);
}

// Round 9
// 1958.078 us; speedup vs baseline: 2.7750x; 1.0149x over previous
//
#include <hip/hip_runtime.h>
#include <math.h>

#define NN 60000
#define BB 8
#define GS 7500   // nodes per graph
#define FF 384
#define EE 600000
#define HH 6
#define CC 10
#define HT_BITS 20
#define HT_SIZE (1u << HT_BITS)
#define HT_MASK (HT_SIZE - 1u)
#define TPB 256
#define CAP 80000  // per-graph edge capacity
#define REMW ((GS + 31) / 32)
#define GPAD 32    // counter padding: one per 128B (R3 lesson)

static inline int ngrid(int n) { return (n + TPB - 1) / TPB; }

// ---------- helpers ----------
__device__ __forceinline__ unsigned int encf(float v) {
  unsigned int b = __float_as_uint(v);
  return (b & 0x80000000u) ? ~b : (b | 0x80000000u);
}
__device__ __forceinline__ float decf(unsigned int u) {
  unsigned int b = (u & 0x80000000u) ? (u & 0x7FFFFFFFu) : ~u;
  return __uint_as_float(b);
}
__device__ __forceinline__ unsigned long long mkprio(float sc, int e) {
  return (((unsigned long long)__float_as_uint(sc)) << 32) |
         (unsigned int)(~(unsigned int)e);
}

// ---------- stage 1 matmul: h1pre = x @ W1 ----------
__global__ void k_mm1(const float* __restrict__ x, const float* __restrict__ W,
                      float* __restrict__ out) {
  __shared__ float Ws[FF * HH];
  for (int i = threadIdx.x; i < FF * HH; i += blockDim.x) Ws[i] = W[i];
  __syncthreads();
  int wave = threadIdx.x >> 6, lane = threadIdx.x & 63;
  int node = blockIdx.x * 4 + wave;
  if (node >= NN) return;
  const float* xr = x + (size_t)node * FF;
  float acc[HH] = {0.f, 0.f, 0.f, 0.f, 0.f, 0.f};
  for (int k = lane; k < FF; k += 64) {
    float xv = xr[k];
#pragma unroll
    for (int j = 0; j < HH; j++) acc[j] += xv * Ws[k * HH + j];
  }
#pragma unroll
  for (int j = 0; j < HH; j++) {
#pragma unroll
    for (int o = 32; o > 0; o >>= 1) acc[j] += __shfl_down(acc[j], o, 64);
  }
  if (lane == 0) {
#pragma unroll
    for (int j = 0; j < HH; j++) out[(size_t)node * HH + j] = acc[j];
  }
}

// ---------- fused per-stage init ----------
__global__ void k_prep(float* __restrict__ deg, unsigned char* __restrict__ hasloop,
                       unsigned int* __restrict__ mEnc, float* __restrict__ ssum,
                       float* __restrict__ hout, int fd, int* __restrict__ gcntsA,
                       int* __restrict__ gcntsB, float* __restrict__ gsum,
                       float* __restrict__ gcnt, const unsigned char* __restrict__ nvin,
                       unsigned char* __restrict__ nvout, float* __restrict__ scale,
                       int* __restrict__ merged, int* __restrict__ partner,
                       unsigned long long* __restrict__ bestA,
                       unsigned long long* __restrict__ bestB,
                       unsigned char* __restrict__ remG) {
  int v = blockIdx.x * blockDim.x + threadIdx.x;
  if (v >= NN) return;
  deg[v] = 0.f;
  hasloop[v] = 0;
  mEnc[v] = 0;
  ssum[v] = 0.f;
  for (int j = 0; j < fd; j++) hout[(size_t)v * fd + j] = 0.f;
  unsigned char nvv = nvin ? nvin[v] : 1;
  nvout[v] = nvv;
  remG[v] = nvv;
  bestA[v] = 0ULL;
  bestB[v] = 0ULL;
  scale[v] = 1.0f;
  if (merged) merged[v] = -1;
  partner[v] = -1;
  if (v < BB * GPAD) { gcntsA[v] = 0; gcntsB[v] = 0; }
  if (v < BB * CC) gsum[v] = 0.f;
  if (v < BB) gcnt[v] = 0.f;
}

// ---------- generic GCN conv pieces ----------
__global__ void k_deg(const int* __restrict__ src, const int* __restrict__ dst,
                      const unsigned char* __restrict__ ev, float* __restrict__ deg,
                      unsigned char* __restrict__ hasloop) {
  int e = blockIdx.x * blockDim.x + threadIdx.x;
  if (e >= EE) return;
  if (ev && !ev[e]) return;
  int d = dst[e];
  atomicAdd(&deg[d], 1.0f);
  if (src[e] == d) hasloop[d] = 1;
}

__global__ void k_dinv(const float* __restrict__ deg, const unsigned char* __restrict__ hasloop,
                       const unsigned char* __restrict__ nv, float* __restrict__ dinv,
                       unsigned char* __restrict__ addloop) {
  int v = blockIdx.x * blockDim.x + threadIdx.x;
  if (v >= NN) return;
  int nvv = nv ? (int)nv[v] : 1;
  unsigned char al = (nvv && !hasloop[v]) ? 1 : 0;
  float d = deg[v] + (float)al;
  dinv[v] = d > 0.f ? 1.0f / sqrtf(fmaxf(d, 1e-12f)) : 0.f;
  addloop[v] = al;
}

__global__ void k_gcn_agg(const int* __restrict__ src, const int* __restrict__ dst,
                          const unsigned char* __restrict__ ev, const float* __restrict__ dinv,
                          const float* __restrict__ h, float* __restrict__ out, int fd) {
  int e = blockIdx.x * blockDim.x + threadIdx.x;
  if (e >= EE) return;
  if (ev && !ev[e]) return;
  int s = src[e], d = dst[e];
  float c = dinv[s] * dinv[d];
  for (int j = 0; j < fd; j++)
    atomicAdd(&out[(size_t)d * fd + j], h[(size_t)s * fd + j] * c);
}

__global__ void k_gcn_fin(const float* __restrict__ h, const float* __restrict__ dinv,
                          const unsigned char* __restrict__ addloop, const float* __restrict__ b,
                          float* __restrict__ out, int fd, int relu) {
  int v = blockIdx.x * blockDim.x + threadIdx.x;
  if (v >= NN) return;
  float c = addloop[v] ? dinv[v] * dinv[v] : 0.f;
  for (int j = 0; j < fd; j++) {
    float o = out[(size_t)v * fd + j] + c * h[(size_t)v * fd + j] + b[j];
    if (relu) o = fmaxf(o, 0.f);
    out[(size_t)v * fd + j] = o;
  }
}

// ---------- edge pool: scores ----------
__global__ void k_raw(const float* __restrict__ x, const int* __restrict__ src,
                      const int* __restrict__ dst, const unsigned char* __restrict__ ev,
                      const float* __restrict__ Wp, const float* __restrict__ bp,
                      float* __restrict__ raw, unsigned int* __restrict__ mEnc, int fd) {
  int e = blockIdx.x * blockDim.x + threadIdx.x;
  if (e >= EE) return;
  if (ev && !ev[e]) return;
  int s = src[e], d = dst[e];
  float r = bp[0];
  for (int j = 0; j < fd; j++) r += x[(size_t)s * fd + j] * Wp[j];
  for (int j = 0; j < fd; j++) r += x[(size_t)d * fd + j] * Wp[fd + j];
  raw[e] = r;
  atomicMax(&mEnc[d], encf(r));
}

__global__ void k_exps(const float* __restrict__ raw, const int* __restrict__ dst,
                       const unsigned char* __restrict__ ev, const unsigned int* __restrict__ mEnc,
                       float* __restrict__ ex, float* __restrict__ ssum) {
  int e = blockIdx.x * blockDim.x + threadIdx.x;
  if (e >= EE) return;
  if (ev && !ev[e]) return;
  int d = dst[e];
  unsigned int me = mEnc[d];
  float m = me ? decf(me) : 0.f;
  float v = expf(raw[e] - m);
  ex[e] = v;
  atomicAdd(&ssum[d], v);
}

// ---------- matching round 1, phase A (full GPU): score + post bestA ----------
__global__ void k_r1post(const int* __restrict__ src, const int* __restrict__ dst,
                         const float* __restrict__ ex, const float* __restrict__ ssum,
                         const unsigned char* __restrict__ ev, const unsigned char* __restrict__ remG,
                         float* __restrict__ score, unsigned long long* __restrict__ bestA,
                         unsigned char* __restrict__ chosen) {
  int e = blockIdx.x * blockDim.x + threadIdx.x;
  if (e >= EE) return;
  chosen[e] = 0;
  if (ev && !ev[e]) return;
  int s = src[e], d = dst[e];
  if (!remG[s] || !remG[d]) return;
  float sd = ssum[d];
  float sc = ex[e] / (sd > 0.f ? sd : 1.0f) + 0.5f;
  score[e] = sc;
  unsigned long long p = mkprio(sc, e);
  atomicMax(&bestA[s], p);
  if (d != s) atomicMax(&bestA[d], p);
}

// ---------- round 1 phase B: select + compact; survivors zero bestB ----------
__global__ void k_r1sel(const int* __restrict__ src, const int* __restrict__ dst,
                        const float* __restrict__ score, const unsigned char* __restrict__ ev,
                        unsigned char* __restrict__ remG,
                        const unsigned long long* __restrict__ bestA,
                        unsigned long long* __restrict__ bestB,
                        unsigned char* __restrict__ chosen, ulonglong2* __restrict__ recs,
                        int* __restrict__ gcnts) {
  __shared__ int wcnt[TPB / 64][BB];
  __shared__ int bbase[BB];
  int e = blockIdx.x * blockDim.x + threadIdx.x;
  int w = threadIdx.x >> 6, lane = threadIdx.x & 63;
  int keep = 0, s = 0, d = 0, g = 0;
  unsigned long long p = 0;
  if (e < EE && (!ev || ev[e])) {
    s = src[e];
    d = dst[e];
    g = s / GS;
    if (remG[s] && remG[d]) {
      p = mkprio(score[e], e);
      if (bestA[s] == p && bestA[d] == p) {
        chosen[e] = 1;
        remG[s] = 0;
        remG[d] = 0;
      } else {
        keep = 1;
        bestB[s] = 0ULL;  // benign write race; next round's buffer
        bestB[d] = 0ULL;
      }
    }
  }
  int myrank = 0;
#pragma unroll
  for (int gg = 0; gg < BB; gg++) {
    unsigned long long m = __ballot(keep && g == gg);
    if (keep && g == gg) myrank = __popcll(m & ((1ULL << lane) - 1ULL));
    if (lane == 0) wcnt[w][gg] = __popcll(m);
  }
  __syncthreads();
  if (threadIdx.x < BB) {
    int gg = threadIdx.x, tot = 0;
#pragma unroll
    for (int ww = 0; ww < TPB / 64; ww++) {
      int c = wcnt[ww][gg];
      wcnt[ww][gg] = tot;
      tot += c;
    }
    bbase[gg] = tot ? atomicAdd(&gcnts[gg * GPAD], tot) : 0;
  }
  __syncthreads();
  if (keep)
    recs[(size_t)g * CAP + bbase[g] + wcnt[w][g] + myrank] =
        make_ulonglong2(p, (((unsigned long long)(unsigned int)s) << 32) | (unsigned int)d);
}

// ---------- generic global round (full GPU) over compacted lists ----------
// post: atomicMax into bestC; also zeroes next round's out-counter.
__global__ void k_gpost(const ulonglong2* __restrict__ recs, const int* __restrict__ gcnts,
                        const unsigned char* __restrict__ remG,
                        unsigned long long* __restrict__ bestC, int* __restrict__ gcntsOut) {
  int g = blockIdx.y;
  if (blockIdx.x == 0 && threadIdx.x == 0) gcntsOut[g * GPAD] = 0;
  int n = gcnts[g * GPAD];
  const ulonglong2* lst = recs + (size_t)g * CAP;
  int stride = gridDim.x * blockDim.x;
  for (int i = blockIdx.x * blockDim.x + threadIdx.x; i < n; i += stride) {
    ulonglong2 r = lst[i];
    int s = (int)(r.y >> 32), d = (int)(r.y & 0xFFFFFFFFu);
    if (remG[s] && remG[d]) {
      atomicMax(&bestC[s], r.x);
      if (d != s) atomicMax(&bestC[d], r.x);
    }
  }
}

// sel: winners commit; survivors -> out list + zero bestN (next buffer)
__global__ void k_gsel(const ulonglong2* __restrict__ recsIn, const int* __restrict__ gcntsIn,
                       unsigned char* __restrict__ remG,
                       const unsigned long long* __restrict__ bestC,
                       unsigned long long* __restrict__ bestN,
                       unsigned char* __restrict__ chosen, ulonglong2* __restrict__ recsOut,
                       int* __restrict__ gcntsOut) {
  int g = blockIdx.y;
  int n = gcntsIn[g * GPAD];
  const ulonglong2* lst = recsIn + (size_t)g * CAP;
  ulonglong2* outl = recsOut + (size_t)g * CAP;
  int lane = threadIdx.x & 63;
  int stride = gridDim.x * blockDim.x;
  for (int i = blockIdx.x * blockDim.x + threadIdx.x; i - lane < n; i += stride) {
    int keep = 0;
    ulonglong2 r;
    if (i < n) {
      r = lst[i];
      int s = (int)(r.y >> 32), d = (int)(r.y & 0xFFFFFFFFu);
      if (remG[s] && remG[d]) {
        if (bestC[s] == r.x && bestC[d] == r.x) {
          int e = (int)(~(unsigned int)(r.x & 0xFFFFFFFFu));
          chosen[e] = 1;
          remG[s] = 0;
          remG[d] = 0;
        } else {
          keep = 1;
          bestN[s] = 0ULL;
          bestN[d] = 0ULL;
        }
      }
    }
    unsigned long long m = __ballot(keep);
    int tot = __popcll(m);
    int pre = __popcll(m & ((1ULL << lane) - 1ULL));
    int b0 = 0;
    if (lane == 0 && tot) b0 = atomicAdd(&gcntsOut[g * GPAD], tot);
    b0 = __shfl(b0, 0, 64);
    if (keep) outl[b0 + pre] = r;
  }
}

// ---------- matching tail: per-graph LDS fixpoint ----------
__global__ __launch_bounds__(1024) void k_match_g(ulonglong2* __restrict__ recs0,
                                                  ulonglong2* __restrict__ recs1,
                                                  const int* __restrict__ gcnts,
                                                  const unsigned char* __restrict__ remG,
                                                  unsigned char* __restrict__ chosen) {
  __shared__ unsigned long long best[GS];
  __shared__ unsigned int remB[REMW];
  __shared__ int cnt_next;
  const int g = blockIdx.x;
  const int base = g * GS;
  const int t = threadIdx.x, nth = blockDim.x;
  const int lane = t & 63;

  for (int w = t; w < REMW; w += nth) {
    unsigned int bits = 0;
    for (int b = 0; b < 32; b++) {
      int v = w * 32 + b;
      if (v < GS) bits |= (remG[base + v] ? 1u : 0u) << b;
    }
    remB[w] = bits;
  }
  for (int i = t; i < GS; i += nth) best[i] = 0ULL;
  __syncthreads();

  ulonglong2* bufs[2] = {recs0 + (size_t)g * CAP, recs1 + (size_t)g * CAP};
  int n = gcnts[g * GPAD];
  int cur = 0;

  while (n > 0) {
    // P1: live edges post priority (x4 batched loads for MLP)
    for (int i0 = 0; i0 < n; i0 += nth * 4) {
      ulonglong2 r[4];
      int have[4];
#pragma unroll
      for (int k = 0; k < 4; k++) {
        int i = i0 + t + k * nth;
        have[k] = i < n;
        if (have[k]) r[k] = bufs[cur][i];
      }
#pragma unroll
      for (int k = 0; k < 4; k++) {
        if (!have[k]) continue;
        int ls = (int)(r[k].y >> 32) - base, ld = (int)(r[k].y & 0xFFFFFFFFu) - base;
        if (((remB[ls >> 5] >> (ls & 31)) & 1u) && ((remB[ld >> 5] >> (ld & 31)) & 1u)) {
          atomicMax(&best[ls], r[k].x);
          if (ld != ls) atomicMax(&best[ld], r[k].x);
        }
      }
    }
    if (t == 0) cnt_next = 0;
    __syncthreads();
    // P2: winners commit; survivors compact
    for (int i0 = 0; i0 < n; i0 += nth * 4) {
      ulonglong2 r[4];
      int have[4];
#pragma unroll
      for (int k = 0; k < 4; k++) {
        int i = i0 + t + k * nth;
        have[k] = i < n;
        if (have[k]) r[k] = bufs[cur][i];
      }
#pragma unroll
      for (int k = 0; k < 4; k++) {
        int keep = 0;
        int ls = 0, ld = 0;
        if (have[k]) {
          ls = (int)(r[k].y >> 32) - base;
          ld = (int)(r[k].y & 0xFFFFFFFFu) - base;
          if (((remB[ls >> 5] >> (ls & 31)) & 1u) && ((remB[ld >> 5] >> (ld & 31)) & 1u)) {
            if (best[ls] == r[k].x && best[ld] == r[k].x) {
              int e = (int)(~(unsigned int)(r[k].x & 0xFFFFFFFFu));
              chosen[e] = 1;
              atomicAnd(&remB[ls >> 5], ~(1u << (ls & 31)));
              atomicAnd(&remB[ld >> 5], ~(1u << (ld & 31)));
            } else {
              keep = 1;
            }
          }
        }
        unsigned long long m = __ballot(keep);
        int tot = __popcll(m);
        int pre = __popcll(m & ((1ULL << lane) - 1ULL));
        int b0 = 0;
        if (lane == 0 && tot) b0 = atomicAdd(&cnt_next, tot);
        b0 = __shfl(b0, 0, 64);
        if (keep) bufs[cur ^ 1][b0 + pre] = r[k];
      }
    }
    __syncthreads();
    n = cnt_next;
    // P3: hybrid clear — survivor-driven for small rounds, full wipe otherwise
    if (n < 4096) {
      for (int i = t; i < n; i += nth) {
        ulonglong2 r = bufs[cur ^ 1][i];
        best[(int)(r.y >> 32) - base] = 0ULL;
        best[(int)(r.y & 0xFFFFFFFFu) - base] = 0ULL;
      }
    } else {
      for (int i = t; i < GS; i += nth) best[i] = 0ULL;
    }
    __syncthreads();
    cur ^= 1;
  }
}

// ---------- edge pool: post-matching ----------
__global__ void k_pool_edge(const int* __restrict__ src, const int* __restrict__ dst,
                            const unsigned char* __restrict__ chosen, const float* __restrict__ score,
                            unsigned char* __restrict__ nvout, float* __restrict__ scale,
                            int* __restrict__ partner, int* __restrict__ merged) {
  int e = blockIdx.x * blockDim.x + threadIdx.x;
  if (e >= EE) return;
  if (!chosen[e]) return;
  int s = src[e], d = dst[e];
  scale[s] = score[e];
  if (merged) merged[d] = s;
  if (s != d) {
    nvout[d] = 0;
    partner[s] = d;
  }
}

// fused: newx1 (never materialized) -> h2pre = newx1 @ W2
__global__ void k_newx_mm2(const float* __restrict__ h1, const int* __restrict__ partner,
                           const float* __restrict__ scale, const unsigned char* __restrict__ nvout,
                           const float* __restrict__ W2, float* __restrict__ h2pre) {
  int v = blockIdx.x * blockDim.x + threadIdx.x;
  if (v >= NN) return;
  float sc = scale[v];
  int ok = nvout[v];
  int p = partner[v];
  float nx[HH];
#pragma unroll
  for (int j = 0; j < HH; j++) {
    float a = h1[(size_t)v * HH + j];
    if (p >= 0) a += h1[(size_t)p * HH + j];
    nx[j] = ok ? a * sc : 0.f;
  }
#pragma unroll
  for (int c = 0; c < CC; c++) {
    float a = 0.f;
#pragma unroll
    for (int j = 0; j < HH; j++) a += nx[j] * W2[j * CC + c];
    h2pre[(size_t)v * CC + c] = a;
  }
}

// fused remap + dedup insert
__device__ __forceinline__ unsigned int ht_hash(unsigned long long key) {
  return (unsigned int)((key * 0x9E3779B97F4A7C15ULL) >> 44) & HT_MASK;
}

__global__ void k_remap_ins(const int* __restrict__ src, const int* __restrict__ dst,
                            const int* __restrict__ merged, int* __restrict__ ns,
                            int* __restrict__ nd, unsigned long long* __restrict__ htab) {
  int e = blockIdx.x * blockDim.x + threadIdx.x;
  if (e >= EE) return;
  int s = src[e], d = dst[e];
  int ms = merged[s], md = merged[d];
  int a = ms >= 0 ? ms : s;
  int b = md >= 0 ? md : d;
  ns[e] = a;
  nd[e] = b;
  unsigned long long key =
      (unsigned long long)((((unsigned int)a) << 16) | (unsigned int)b);
  unsigned long long val = (key << 32) | (unsigned int)e;
  unsigned int h = ht_hash(key);
  for (;;) {
    unsigned long long curv = htab[h];
    if (curv == ~0ULL) {
      unsigned long long prev = atomicCAS(&htab[h], ~0ULL, val);
      if (prev == ~0ULL) break;
      curv = prev;
    }
    if ((curv >> 32) == key) {
      atomicMin(&htab[h], val);
      break;
    }
    h = (h + 1) & HT_MASK;
  }
}

__global__ void k_dedup_mark(const int* __restrict__ ns, const int* __restrict__ nd,
                             const unsigned long long* __restrict__ htab,
                             unsigned char* __restrict__ evout) {
  int e = blockIdx.x * blockDim.x + threadIdx.x;
  if (e >= EE) return;
  unsigned long long key =
      (unsigned long long)((((unsigned int)ns[e]) << 16) | (unsigned int)nd[e]);
  unsigned int h = ht_hash(key);
  for (;;) {
    unsigned long long curv = htab[h];
    if ((curv >> 32) == key) {
      evout[e] = ((curv & 0xFFFFFFFFULL) == (unsigned long long)(unsigned int)e) ? 1 : 0;
      return;
    }
    h = (h + 1) & HT_MASK;
  }
}

// fused: newx2 (never materialized) -> graph mean-pool accumulate
__global__ void k_newx_pool(const float* __restrict__ h2, const int* __restrict__ partner,
                            const float* __restrict__ scale, const unsigned char* __restrict__ nv,
                            float* __restrict__ gsum, float* __restrict__ gcnt) {
  int v = blockIdx.x * blockDim.x + threadIdx.x;
  int lane = threadIdx.x & 63;
  int b = (v < NN ? v : NN - 1) / GS;
  int active = (v < NN) && nv[v];
  float cnt = active ? 1.f : 0.f;
  float val[CC];
  if (active) {
    float sc = scale[v];
    int p = partner[v];
    for (int j = 0; j < CC; j++) {
      float a = h2[(size_t)v * CC + j];
      if (p >= 0) a += h2[(size_t)p * CC + j];
      val[j] = a * sc;
    }
  } else {
    for (int j = 0; j < CC; j++) val[j] = 0.f;
  }
  int b0 = __shfl(b, 0, 64);
  unsigned long long same = __ballot(b == b0);
  if (same == ~0ULL) {
    for (int o = 32; o > 0; o >>= 1) {
      cnt += __shfl_down(cnt, o, 64);
      for (int j = 0; j < CC; j++) val[j] += __shfl_down(val[j], o, 64);
    }
    if (lane == 0 && cnt > 0.f) {
      atomicAdd(&gcnt[b0], cnt);
      for (int j = 0; j < CC; j++) atomicAdd(&gsum[b0 * CC + j], val[j]);
    }
  } else if (active) {
    atomicAdd(&gcnt[b], cnt);
    for (int j = 0; j < CC; j++) atomicAdd(&gsum[b * CC + j], val[j]);
  }
}

__global__ void k_logsm(const float* __restrict__ gsum, const float* __restrict__ gcnt,
                        float* __restrict__ out) {
  int t = threadIdx.x;
  if (t >= BB) return;
  float gr[CC];
  float c = gcnt[t];
  float m = -INFINITY;
  for (int j = 0; j < CC; j++) {
    gr[j] = gsum[t * CC + j] / c;
    m = fmaxf(m, gr[j]);
  }
  float s = 0.f;
  for (int j = 0; j < CC; j++) s += expf(gr[j] - m);
  float l = logf(s);
  for (int j = 0; j < CC; j++) out[t * CC + j] = gr[j] - m - l;
}

// ---------- host ----------
extern "C" void kernel_launch(void* const* d_in, const int* in_sizes, int n_in,
                              void* d_out, int out_size, void* d_ws, size_t ws_size,
                              hipStream_t stream) {
  const float* x = (const float*)d_in[0];
  const int* src = (const int*)d_in[1];
  const int* dst = (const int*)d_in[2];
  const float* W1 = (const float*)d_in[4];
  const float* b1 = (const float*)d_in[5];
  const float* W2 = (const float*)d_in[6];
  const float* b2 = (const float*)d_in[7];
  const float* Wp1 = (const float*)d_in[8];
  const float* bp1 = (const float*)d_in[9];
  const float* Wp2 = (const float*)d_in[10];
  const float* bp2 = (const float*)d_in[11];
  float* out = (float*)d_out;

  char* wsb = (char*)d_ws;
  size_t off = 0;
  auto A = [&](size_t bytes) -> char* {
    char* r = wsb + off;
    off = (off + bytes + 255) & ~(size_t)255;
    return r;
  };
  float* h1pre = (float*)A((size_t)NN * HH * 4);
  float* h1out = (float*)A((size_t)NN * HH * 4);
  float* deg = (float*)A((size_t)NN * 4);
  float* dinv = (float*)A((size_t)NN * 4);
  unsigned char* hasloop = (unsigned char*)A(NN);
  unsigned char* addloop = (unsigned char*)A(NN);
  float* raw = (float*)A((size_t)EE * 4);
  float* ex = (float*)A((size_t)EE * 4);
  float* score = (float*)A((size_t)EE * 4);
  unsigned int* mEnc = (unsigned int*)A((size_t)NN * 4);
  float* ssum = (float*)A((size_t)NN * 4);
  unsigned char* chosen = (unsigned char*)A(EE);
  unsigned char* nv1 = (unsigned char*)A(NN);
  unsigned char* nv2 = (unsigned char*)A(NN);
  float* scale = (float*)A((size_t)NN * 4);
  int* partner = (int*)A((size_t)NN * 4);
  int* merged = (int*)A((size_t)NN * 4);
  int* ns = (int*)A((size_t)EE * 4);
  int* nd = (int*)A((size_t)EE * 4);
  unsigned char* ev1 = (unsigned char*)A(EE);
  unsigned long long* htab = (unsigned long long*)A((size_t)HT_SIZE * 8);
  float* h2pre = (float*)A((size_t)NN * CC * 4);
  float* h2out = (float*)A((size_t)NN * CC * 4);
  unsigned long long* bestA = (unsigned long long*)A((size_t)NN * 8);
  unsigned long long* bestB = (unsigned long long*)A((size_t)NN * 8);
  unsigned char* remG = (unsigned char*)A(NN);
  ulonglong2* recs0 = (ulonglong2*)A((size_t)BB * CAP * 16);
  ulonglong2* recs1 = (ulonglong2*)A((size_t)BB * CAP * 16);
  int* gcntsA = (int*)A((size_t)BB * GPAD * 4);
  int* gcntsB = (int*)A((size_t)BB * GPAD * 4);
  float* gsum = (float*)A((size_t)BB * CC * 4);
  float* gcnt = (float*)A((size_t)BB * 4);
  (void)ws_size; (void)n_in; (void)in_sizes; (void)out_size;

  const int GE = ngrid(EE), GN = ngrid(NN);
  const dim3 RG(32, BB);  // global-round grid: 32 blocks x 8 graphs

  // ===== stage 1: GCNConv(384->6) + ReLU =====
  hipMemsetAsync(htab, 0xFF, (size_t)HT_SIZE * 8, stream);
  hipLaunchKernelGGL(k_mm1, dim3((NN + 3) / 4), dim3(TPB), 0, stream, x, W1, h1pre);
  hipLaunchKernelGGL(k_prep, dim3(GN), dim3(TPB), 0, stream, deg, hasloop, mEnc, ssum, h1out, HH, gcntsA, gcntsB,
                     gsum, gcnt, (const unsigned char*)nullptr, nv1, scale, merged, partner, bestA, bestB, remG);
  hipLaunchKernelGGL(k_deg, dim3(GE), dim3(TPB), 0, stream, src, dst, (const unsigned char*)nullptr, deg, hasloop);
  hipLaunchKernelGGL(k_dinv, dim3(GN), dim3(TPB), 0, stream, deg, hasloop, (const unsigned char*)nullptr, dinv, addloop);
  hipLaunchKernelGGL(k_gcn_agg, dim3(GE), dim3(TPB), 0, stream, src, dst, (const unsigned char*)nullptr, dinv, h1pre, h1out, HH);
  hipLaunchKernelGGL(k_gcn_fin, dim3(GN), dim3(TPB), 0, stream, h1pre, dinv, addloop, b1, h1out, HH, 1);

  // ===== edge pool 1 =====
  hipLaunchKernelGGL(k_raw, dim3(GE), dim3(TPB), 0, stream, h1out, src, dst, (const unsigned char*)nullptr, Wp1, bp1, raw, mEnc, HH);
  hipLaunchKernelGGL(k_exps, dim3(GE), dim3(TPB), 0, stream, raw, dst, (const unsigned char*)nullptr, mEnc, ex, ssum);
  hipLaunchKernelGGL(k_r1post, dim3(GE), dim3(TPB), 0, stream, src, dst, ex, ssum, (const unsigned char*)nullptr, remG, score, bestA, chosen);
  hipLaunchKernelGGL(k_r1sel, dim3(GE), dim3(TPB), 0, stream, src, dst, score, (const unsigned char*)nullptr, remG, bestA, bestB, chosen, recs0, gcntsA);
  // global rounds 2-4
  hipLaunchKernelGGL(k_gpost, RG, dim3(TPB), 0, stream, recs0, gcntsA, remG, bestB, gcntsB);
  hipLaunchKernelGGL(k_gsel, RG, dim3(TPB), 0, stream, recs0, gcntsA, remG, bestB, bestA, chosen, recs1, gcntsB);
  hipLaunchKernelGGL(k_gpost, RG, dim3(TPB), 0, stream, recs1, gcntsB, remG, bestA, gcntsA);
  hipLaunchKernelGGL(k_gsel, RG, dim3(TPB), 0, stream, recs1, gcntsB, remG, bestA, bestB, chosen, recs0, gcntsA);
  hipLaunchKernelGGL(k_gpost, RG, dim3(TPB), 0, stream, recs0, gcntsA, remG, bestB, gcntsB);
  hipLaunchKernelGGL(k_gsel, RG, dim3(TPB), 0, stream, recs0, gcntsA, remG, bestB, bestA, chosen, recs1, gcntsB);
  // LDS tail
  hipLaunchKernelGGL(k_match_g, dim3(BB), dim3(1024), 0, stream, recs1, recs0, gcntsB, remG, chosen);
  hipLaunchKernelGGL(k_pool_edge, dim3(GE), dim3(TPB), 0, stream, src, dst, chosen, score, nv1, scale, partner, merged);
  hipLaunchKernelGGL(k_newx_mm2, dim3(GN), dim3(TPB), 0, stream, h1out, partner, scale, nv1, W2, h2pre);
  hipLaunchKernelGGL(k_remap_ins, dim3(GE), dim3(TPB), 0, stream, src, dst, merged, ns, nd, htab);
  hipLaunchKernelGGL(k_dedup_mark, dim3(GE), dim3(TPB), 0, stream, ns, nd, htab, ev1);

  // ===== stage 2: GCNConv(6->10) =====
  hipLaunchKernelGGL(k_prep, dim3(GN), dim3(TPB), 0, stream, deg, hasloop, mEnc, ssum, h2out, CC, gcntsA, gcntsB,
                     gsum, gcnt, (const unsigned char*)nv1, nv2, scale, (int*)nullptr, partner, bestA, bestB, remG);
  hipLaunchKernelGGL(k_deg, dim3(GE), dim3(TPB), 0, stream, ns, nd, (const unsigned char*)ev1, deg, hasloop);
  hipLaunchKernelGGL(k_dinv, dim3(GN), dim3(TPB), 0, stream, deg, hasloop, (const unsigned char*)nv1, dinv, addloop);
  hipLaunchKernelGGL(k_gcn_agg, dim3(GE), dim3(TPB), 0, stream, ns, nd, (const unsigned char*)ev1, dinv, h2pre, h2out, CC);
  hipLaunchKernelGGL(k_gcn_fin, dim3(GN), dim3(TPB), 0, stream, h2pre, dinv, addloop, b2, h2out, CC, 0);

  // ===== edge pool 2 =====
  hipLaunchKernelGGL(k_raw, dim3(GE), dim3(TPB), 0, stream, h2out, ns, nd, (const unsigned char*)ev1, Wp2, bp2, raw, mEnc, CC);
  hipLaunchKernelGGL(k_exps, dim3(GE), dim3(TPB), 0, stream, raw, nd, (const unsigned char*)ev1, mEnc, ex, ssum);
  hipLaunchKernelGGL(k_r1post, dim3(GE), dim3(TPB), 0, stream, ns, nd, ex, ssum, (const unsigned char*)ev1, remG, score, bestA, chosen);
  hipLaunchKernelGGL(k_r1sel, dim3(GE), dim3(TPB), 0, stream, ns, nd, score, (const unsigned char*)ev1, remG, bestA, bestB, chosen, recs0, gcntsA);
  hipLaunchKernelGGL(k_gpost, RG, dim3(TPB), 0, stream, recs0, gcntsA, remG, bestB, gcntsB);
  hipLaunchKernelGGL(k_gsel, RG, dim3(TPB), 0, stream, recs0, gcntsA, remG, bestB, bestA, chosen, recs1, gcntsB);
  hipLaunchKernelGGL(k_gpost, RG, dim3(TPB), 0, stream, recs1, gcntsB, remG, bestA, gcntsA);
  hipLaunchKernelGGL(k_gsel, RG, dim3(TPB), 0, stream, recs1, gcntsB, remG, bestA, bestB, chosen, recs0, gcntsA);
  hipLaunchKernelGGL(k_gpost, RG, dim3(TPB), 0, stream, recs0, gcntsA, remG, bestB, gcntsB);
  hipLaunchKernelGGL(k_gsel, RG, dim3(TPB), 0, stream, recs0, gcntsA, remG, bestB, bestA, chosen, recs1, gcntsB);
  hipLaunchKernelGGL(k_match_g, dim3(BB), dim3(1024), 0, stream, recs1, recs0, gcntsB, remG, chosen);
  hipLaunchKernelGGL(k_pool_edge, dim3(GE), dim3(TPB), 0, stream, ns, nd, chosen, score, nv2, scale, partner, (int*)nullptr);

  // ===== readout =====
  hipLaunchKernelGGL(k_newx_pool, dim3(GN), dim3(TPB), 0, stream, h2out, partner, scale, nv2, gsum, gcnt);
  hipLaunchKernelGGL(k_logsm, dim3(1), dim3(64), 0, stream, gsum, gcnt, out);
}